// Round 5
// baseline (200.869 us; speedup 1.0000x reference)
//
#include <hip/hip_runtime.h>
#include <float.h>
#include <math.h>

#define NT 256
#define NW (NT / 64)
#define S 16
#define NB 512
#define CAP1 1024
#define CAP2 1024
#define SCAP 512
#define LT 140
#define TGT 128
#define XMIN (-8.0f)
#define BINW (1.0f / 32.0f)
#define INVW (32.0f)
#define SEPS 1e-5f

__device__ __forceinline__ int binOf(float x) {
  int bn = (int)floorf((x - XMIN) * INVW);
  return bn < 0 ? 0 : (bn > NB - 1 ? NB - 1 : bn);
}
__device__ __forceinline__ unsigned f2k(float f) {
  unsigned u = __float_as_uint(f);
  return (u & 0x80000000u) ? ~u : (u | 0x80000000u);
}
__device__ __forceinline__ float k2f(unsigned k) {
  return __uint_as_float((k & 0x80000000u) ? (k ^ 0x80000000u) : ~k);
}

// K1: ONE pass over logits: wave-priv hist + slice max; then L2-hot re-read of
// own slice: exact slice sumexp, argmax-by-equality, collect slice-local top-LT.
__global__ __launch_bounds__(NT) void k1(const float* __restrict__ logits,
    int V, int CS, int* __restrict__ histS, float* __restrict__ sMax,
    int* __restrict__ sArg, float* __restrict__ sSum,
    float* __restrict__ scandV, int* __restrict__ scandI, int* __restrict__ scnt)
{
  const int s = blockIdx.x, b = blockIdx.y, tid = threadIdx.x;
  const int wid = tid >> 6;
  const float* lrow = logits + (size_t)b * V;
  const int lo = s * CS, hi = min(V, lo + CS);
  __shared__ int lh[4 * NB];
  __shared__ float wv[NW];
  __shared__ float shMax, shEdge;
  __shared__ int qn, shArg;
  __shared__ float qv[SCAP]; __shared__ int qi[SCAP];
  for (int j = tid; j < 4 * NB; j += NT) lh[j] = 0;
  if (tid == 0) { qn = 0; shArg = 0x7fffffff; }
  __syncthreads();

  const int vecEnd = lo + ((hi - lo) & ~3);
  const float4* l4 = reinterpret_cast<const float4*>(lrow);
  float bm = -FLT_MAX;
  int* lhw = &lh[wid * NB];
  for (int i4 = (lo >> 2) + tid; i4 < (vecEnd >> 2); i4 += NT) {
    float4 x = l4[i4];
    bm = fmaxf(bm, fmaxf(fmaxf(x.x, x.y), fmaxf(x.z, x.w)));
    atomicAdd(&lhw[binOf(x.x)], 1);
    atomicAdd(&lhw[binOf(x.y)], 1);
    atomicAdd(&lhw[binOf(x.z)], 1);
    atomicAdd(&lhw[binOf(x.w)], 1);
  }
  for (int i = vecEnd + tid; i < hi; i += NT) {
    float x = lrow[i];
    bm = fmaxf(bm, x);
    atomicAdd(&lhw[binOf(x)], 1);
  }
  for (int off = 32; off; off >>= 1) bm = fmaxf(bm, __shfl_down(bm, off));
  if ((tid & 63) == 0) wv[wid] = bm;
  __syncthreads();
  // merge wave-priv hists; store slice hist; keep merged copy in lh[0..NB)
  int* hslice = histS + ((size_t)b * S + s) * NB;
  for (int j = tid; j < NB; j += NT) {
    int tot = lh[j] + lh[NB + j] + lh[2 * NB + j] + lh[3 * NB + j];
    lh[j] = tot;
    hslice[j] = tot;
  }
  if (tid == 0) {
    float m = wv[0];
    for (int w = 1; w < NW; w++) m = fmaxf(m, wv[w]);
    shMax = m;
  }
  __syncthreads();
  if (tid == 0) {
    int cum = 0, jsel = 0;
    for (int j = NB - 1; j >= 0; j--) {
      cum += lh[j];
      if (cum >= LT) { jsel = j; break; }
    }
    shEdge = XMIN + jsel * BINW;
  }
  __syncthreads();
  const float Ml = shMax, edge = shEdge;
  float sum = 0.0f;
  for (int i4 = (lo >> 2) + tid; i4 < (vecEnd >> 2); i4 += NT) {
    float4 x = l4[i4];
    int base = i4 << 2;
    sum += expf(x.x - Ml) + expf(x.y - Ml) + expf(x.z - Ml) + expf(x.w - Ml);
    float xs[4] = {x.x, x.y, x.z, x.w};
    #pragma unroll
    for (int q = 0; q < 4; q++) {
      if (xs[q] >= edge) {
        int p2 = atomicAdd(&qn, 1);
        if (p2 < SCAP) { qv[p2] = xs[q]; qi[p2] = base + q; }
      }
      if (xs[q] == Ml) atomicMin(&shArg, base + q);
    }
  }
  for (int i = vecEnd + tid; i < hi; i += NT) {
    float x = lrow[i];
    sum += expf(x - Ml);
    if (x >= edge) {
      int p2 = atomicAdd(&qn, 1);
      if (p2 < SCAP) { qv[p2] = x; qi[p2] = i; }
    }
    if (x == Ml) atomicMin(&shArg, i);
  }
  for (int off = 32; off; off >>= 1) sum += __shfl_down(sum, off);
  if ((tid & 63) == 0) wv[wid] = sum;
  __syncthreads();
  if (tid == 0) {
    float ts = 0.0f;
    for (int w = 0; w < NW; w++) ts += wv[w];
    sSum[b * S + s] = ts;
    sMax[b * S + s] = shMax;
    sArg[b * S + s] = shArg;
    scnt[b * S + s] = min(qn, SCAP);
  }
  __syncthreads();
  int qc = min(qn, SCAP);
  float* cvs = scandV + ((size_t)b * S + s) * SCAP;
  int*   cis = scandI + ((size_t)b * S + s) * SCAP;
  for (int j = tid; j < qc; j += NT) { cvs[j] = qv[j]; cis[j] = qi[j]; }
}

// K2: sum slice hists -> global edge; M/gidx; exact logZ; mode; zero cnt2
__global__ __launch_bounds__(NT) void k2(const float* __restrict__ temp,
    const float* __restrict__ topp, const int* __restrict__ topk,
    const int* __restrict__ histS, const float* __restrict__ sMax,
    const int* __restrict__ sArg, const float* __restrict__ sSum,
    float* __restrict__ rowF, int* __restrict__ rowI, int* __restrict__ cnt2)
{
  const int b = blockIdx.x, tid = threadIdx.x;
  __shared__ int lc[NB];
  __shared__ float sMx[S], sSm[S]; __shared__ int sAg[S];
  for (int j = tid; j < NB; j += NT) {
    int tot = 0;
    for (int s2 = 0; s2 < S; s2++) tot += histS[((size_t)b * S + s2) * NB + j];
    lc[j] = tot;
  }
  if (tid < S) {
    sMx[tid] = sMax[b * S + tid];
    sSm[tid] = sSum[b * S + tid];
    sAg[tid] = sArg[b * S + tid];
  }
  __syncthreads();
  if (tid == 0) {
    float M = -FLT_MAX; int gi = 0x7fffffff;
    for (int s2 = 0; s2 < S; s2++) {
      float v = sMx[s2]; int ii = sAg[s2];
      if (v > M || (v == M && ii < gi)) { M = v; gi = ii; }
    }
    float Z = 0.0f;
    for (int s2 = 0; s2 < S; s2++) Z += sSm[s2] * expf(sMx[s2] - M);
    float logZ = logf(Z);
    int cum = 0, bsel = 0;
    for (int j = NB - 1; j >= 0; j--) {
      cum += lc[j];
      if (cum >= TGT) { bsel = j; break; }
    }
    int bc = (bsel >= 2) ? (bsel - 2) : 0;
    float t = temp[b]; float p = topp[b]; int k = topk[b];
    int mode = (t < SEPS) ? 0 : ((k >= 1) ? 1 : 2);
    rowF[b * 16 + 0] = M;
    rowF[b * 16 + 1] = logZ;
    rowF[b * 16 + 2] = XMIN + bc * BINW;
    rowF[b * 16 + 3] = (t >= SEPS) ? (M / t) : 0.0f;
    rowF[b * 16 + 4] = t;
    rowF[b * 16 + 5] = p;
    rowI[b * 16 + 0] = gi;
    rowI[b * 16 + 1] = mode;
    rowI[b * 16 + 2] = k;
    cnt2[b] = 0;
  }
}

// K3 (mode-2 rows only): mass histogram per slice (wave-privatized)
__global__ __launch_bounds__(NT) void k3(const float* __restrict__ logits,
    int V, int CS, const float* __restrict__ rowF, const int* __restrict__ rowI,
    float* __restrict__ massS)
{
  const int s = blockIdx.x, b = blockIdx.y, tid = threadIdx.x;
  if (rowI[b * 16 + 1] != 2) return;
  const int wid = tid >> 6;
  const float Ms = rowF[b * 16 + 3];
  const float t = rowF[b * 16 + 4];
  const float* lrow = logits + (size_t)b * V;
  const int lo = s * CS, hi = min(V, lo + CS);
  __shared__ float lm[4 * NB];
  for (int j = tid; j < 4 * NB; j += NT) lm[j] = 0.0f;
  __syncthreads();
  float* lmw = &lm[wid * NB];
  const int vecEnd = lo + ((hi - lo) & ~3);
  const float4* l4 = reinterpret_cast<const float4*>(lrow);
  for (int i4 = (lo >> 2) + tid; i4 < (vecEnd >> 2); i4 += NT) {
    float4 x = l4[i4];
    atomicAdd(&lmw[binOf(x.x)], expf(x.x / t - Ms));
    atomicAdd(&lmw[binOf(x.y)], expf(x.y / t - Ms));
    atomicAdd(&lmw[binOf(x.z)], expf(x.z / t - Ms));
    atomicAdd(&lmw[binOf(x.w)], expf(x.w / t - Ms));
  }
  for (int i = vecEnd + tid; i < hi; i += NT)
    atomicAdd(&lmw[binOf(lrow[i])], expf(lrow[i] / t - Ms));
  __syncthreads();
  float* mslice = massS + ((size_t)b * S + s) * NB;
  for (int j = tid; j < NB; j += NT)
    mslice[j] = lm[j] + lm[NB + j] + lm[2 * NB + j] + lm[3 * NB + j];
}

// K4: pool slice-candidates, filter by global edge, sort; top-K out;
// modes 0/1: sample + rank + finalize.  mode 2: mass scan -> boundary bin.
__global__ __launch_bounds__(NT) void k4(const float* __restrict__ logits,
    const float* __restrict__ noise, int V, int K,
    const float* __restrict__ scandV, const int* __restrict__ scandI,
    const int* __restrict__ scnt, const float* __restrict__ massS,
    float* __restrict__ rowF, int* __restrict__ rowI,
    float* __restrict__ out, int Bn)
{
  const int b = blockIdx.x, tid = threadIdx.x;
  __shared__ float cv[CAP1]; __shared__ int ci[CAP1];
  __shared__ float sv[CAP1]; __shared__ int si[CAP1];
  __shared__ float ev[CAP1];
  __shared__ float lmass[NB];
  __shared__ float fsum[NT];
  __shared__ float wv[NW]; __shared__ int wi[NW];
  __shared__ int shI[2]; __shared__ float shF[2];
  __shared__ int nn; __shared__ int scl[S];
  const float M = rowF[b * 16 + 0], logZ = rowF[b * 16 + 1], Ms = rowF[b * 16 + 3];
  const float t = rowF[b * 16 + 4], p = rowF[b * 16 + 5];
  const float edgeC = rowF[b * 16 + 2];
  const int mode = rowI[b * 16 + 1], k = rowI[b * 16 + 2], gidx = rowI[b * 16 + 0];
  if (tid == 0) nn = 0;
  if (tid < S) scl[tid] = scnt[b * S + tid];
  __syncthreads();
  for (int s2 = 0; s2 < S; s2++) {
    const float* cvs = scandV + ((size_t)b * S + s2) * SCAP;
    const int*   cis = scandI + ((size_t)b * S + s2) * SCAP;
    int c = scl[s2];
    for (int j = tid; j < c; j += NT) {
      float x = cvs[j];
      if (x >= edgeC) {
        int p2 = atomicAdd(&nn, 1);
        if (p2 < CAP1) { cv[p2] = x; ci[p2] = cis[j]; }
      }
    }
  }
  __syncthreads();
  const int n = min(nn, CAP1);
  for (int c = tid; c < n; c += NT) {
    float v = cv[c]; int id = ci[c]; int r = 0;
    for (int j = 0; j < n; j++) {
      float w = cv[j];
      r += (w > v) || (w == v && ci[j] < id);
    }
    sv[r] = v; si[r] = id;
  }
  __syncthreads();
  float* out_idx = out + Bn;
  float* out_lp  = out + Bn + (size_t)Bn * (K + 1);
  for (int j = tid; j < K && j < n; j += NT) {
    out_idx[(size_t)b * (K + 1) + 1 + j] = (float)si[j];
    out_lp [(size_t)b * (K + 1) + 1 + j] = (sv[j] - M) - logZ;
  }

  if (mode == 2) {
    for (int j = tid; j < NB; j += NT) {
      float tot = 0.0f;
      for (int s2 = 0; s2 < S; s2++) tot += massS[((size_t)b * S + s2) * NB + j];
      lmass[j] = tot;
    }
    __syncthreads();
    const int CH = NB / NT;
    float cs = 0.0f;
    for (int j = tid * CH; j < (tid + 1) * CH; j++) cs += lmass[j];
    fsum[tid] = cs;
    __syncthreads();
    if (tid == 0) {
      float Z2 = 0.0f;
      for (int c = 0; c < NT; c++) Z2 += fsum[c];
      float W = p * Z2;
      float ca = 0.0f; int c = NT - 1;
      for (; c >= 0; c--) {
        if (ca + fsum[c] >= W) break;
        ca += fsum[c];
      }
      if (c < 0) c = 0;
      int Bb = c * CH, found = -1;
      for (int j = c * CH + CH - 1; j >= c * CH; j--) {
        if (ca + lmass[j] >= W) { found = j; break; }
        ca += lmass[j];
      }
      if (found >= 0) Bb = found;
      rowF[b * 16 + 6] = W; rowF[b * 16 + 7] = ca; rowI[b * 16 + 3] = Bb;
    }
    return;
  }

  int smp; float lx;
  if (mode == 0) {
    smp = gidx; lx = M;
  } else {
    const int keff = min(k, n);
    for (int j = tid; j < keff; j += NT) ev[j] = expf(sv[j] / t - Ms);
    __syncthreads();
    if (tid == 0) {
      float Z = 0.0f;
      for (int j = 0; j < keff; j++) Z += ev[j];
      float W = p * Z;
      float cum = 0.0f; int m = 0;
      for (int j = 0; j < keff; j++) {
        if (cum < W) m++; else break;
        cum += ev[j];
      }
      shI[0] = m;
    }
    __syncthreads();
    const int m = shI[0];
    float key = -FLT_MAX; int kid = 0x7fffffff;
    for (int j = tid; j < m; j += NT) {
      float u = noise[(size_t)b * V + si[j]];
      float g = -logf(-logf(u));
      float kk = sv[j] / t + g;
      if (kk > key || (kk == key && si[j] < kid)) { key = kk; kid = si[j]; }
    }
    for (int off = 32; off; off >>= 1) {
      float ov = __shfl_down(key, off);
      int   oi = __shfl_down(kid, off);
      if (ov > key || (ov == key && oi < kid)) { key = ov; kid = oi; }
    }
    if ((tid & 63) == 0) { wv[tid >> 6] = key; wi[tid >> 6] = kid; }
    __syncthreads();
    if (tid == 0) {
      for (int w2 = 1; w2 < NW; w2++)
        if (wv[w2] > key || (wv[w2] == key && wi[w2] < kid)) { key = wv[w2]; kid = wi[w2]; }
      shI[1] = (kid == 0x7fffffff) ? 0 : kid;
    }
    __syncthreads();
    smp = shI[1];
    if (tid == 0) shF[0] = logits[(size_t)b * V + smp];
    __syncthreads();
    lx = shF[0];
  }
  const float tlp = (lx - M) - logZ;
  int rc = 0;
  for (int j = tid; j < n; j += NT) rc += (((sv[j] - M) - logZ) >= tlp) ? 1 : 0;
  for (int off = 32; off; off >>= 1) rc += __shfl_down(rc, off);
  __syncthreads();
  if ((tid & 63) == 0) wi[tid >> 6] = rc;
  __syncthreads();
  if (tid == 0) {
    int rank = 0;
    for (int w2 = 0; w2 < NW; w2++) rank += wi[w2];
    out[b] = (float)smp;
    out_idx[(size_t)b * (K + 1)] = (float)smp;
    out_lp [(size_t)b * (K + 1)] = tlp;
    out[Bn + 2 * (size_t)Bn * (K + 1) + b] = (float)rank;
  }
}

// K5 (mode2): collect boundary-bin elements + above-bin gumbel partials
__global__ __launch_bounds__(NT) void k5(const float* __restrict__ logits,
    const float* __restrict__ noise, int V, int CS,
    const float* __restrict__ rowF, const int* __restrict__ rowI,
    float* __restrict__ l2V, int* __restrict__ l2I, int* __restrict__ cnt2,
    float* __restrict__ gbK, int* __restrict__ gbI)
{
  const int s = blockIdx.x, b = blockIdx.y, tid = threadIdx.x;
  if (rowI[b * 16 + 1] != 2) return;
  const int Bb = rowI[b * 16 + 3];
  const float t = rowF[b * 16 + 4];
  const float* lrow = logits + (size_t)b * V;
  const float* nrow = noise + (size_t)b * V;
  const int lo = s * CS, hi = min(V, lo + CS);
  __shared__ int qn; __shared__ int sbase;
  __shared__ float qv[SCAP]; __shared__ int qi[SCAP];
  __shared__ float wv[NW]; __shared__ int wi[NW];
  if (tid == 0) qn = 0;
  __syncthreads();
  float key = -FLT_MAX; int kid = 0x7fffffff;
  for (int i = lo + tid; i < hi; i += NT) {
    float x = lrow[i];
    int bn = binOf(x);
    if (bn > Bb) {
      float g = -logf(-logf(nrow[i]));
      float kk = x / t + g;
      if (kk > key || (kk == key && i < kid)) { key = kk; kid = i; }
    } else if (bn == Bb) {
      int ppos = atomicAdd(&qn, 1);
      if (ppos < SCAP) { qv[ppos] = x; qi[ppos] = i; }
    }
  }
  for (int off = 32; off; off >>= 1) {
    float ov = __shfl_down(key, off);
    int   oi = __shfl_down(kid, off);
    if (ov > key || (ov == key && oi < kid)) { key = ov; kid = oi; }
  }
  if ((tid & 63) == 0) { wv[tid >> 6] = key; wi[tid >> 6] = kid; }
  __syncthreads();
  if (tid == 0) {
    for (int w = 1; w < NW; w++)
      if (wv[w] > key || (wv[w] == key && wi[w] < kid)) { key = wv[w]; kid = wi[w]; }
    gbK[b * S + s] = key; gbI[b * S + s] = kid;
  }
  int qc = min(qn, SCAP);
  if (tid == 0) sbase = atomicAdd(&cnt2[b], qc);
  __syncthreads();
  for (int j = tid; j < qc; j += NT) {
    int dst = sbase + j;
    if (dst < CAP2) { l2V[b * CAP2 + dst] = qv[j]; l2I[b * CAP2 + dst] = qi[j]; }
  }
}

// K6 (mode2): sort bin, exact prefix, sample, bisect xcrit, finalize
__global__ __launch_bounds__(NT) void k6(const float* __restrict__ logits,
    const float* __restrict__ noise, int V, int K,
    const float* __restrict__ l2V, const int* __restrict__ l2I,
    const int* __restrict__ cnt2,
    const float* __restrict__ gbK, const int* __restrict__ gbI,
    float* __restrict__ rowF, const int* __restrict__ rowI,
    float* __restrict__ out, int Bn)
{
  const int b = blockIdx.x, tid = threadIdx.x;
  if (rowI[b * 16 + 1] != 2) return;
  __shared__ float cv[CAP2]; __shared__ int ci2[CAP2];
  __shared__ float sv[CAP2]; __shared__ int si2[CAP2];
  __shared__ float ev[CAP2];
  __shared__ float wv[NW]; __shared__ int wi[NW];
  __shared__ int shI[2];
  const int n2 = min(cnt2[b], CAP2);
  const float M = rowF[b * 16 + 0], logZ = rowF[b * 16 + 1], Ms = rowF[b * 16 + 3];
  const float t = rowF[b * 16 + 4];
  const float W = rowF[b * 16 + 6], CAv = rowF[b * 16 + 7];
  for (int j = tid; j < n2; j += NT) { cv[j] = l2V[b * CAP2 + j]; ci2[j] = l2I[b * CAP2 + j]; }
  __syncthreads();
  for (int c = tid; c < n2; c += NT) {
    float v = cv[c]; int id = ci2[c]; int r = 0;
    for (int j = 0; j < n2; j++) {
      float w = cv[j];
      r += (w > v) || (w == v && ci2[j] < id);
    }
    sv[r] = v; si2[r] = id;
  }
  __syncthreads();
  for (int j = tid; j < n2; j += NT) ev[j] = expf(sv[j] / t - Ms);
  __syncthreads();
  if (tid == 0) {
    float cum = CAv; int last = -1;
    for (int j = 0; j < n2; j++) {
      if (cum < W) last = j; else break;
      cum += ev[j];
    }
    shI[0] = last;
  }
  __syncthreads();
  const int last = shI[0];
  float key = -FLT_MAX; int kid = 0x7fffffff;
  for (int j = tid; j <= last; j += NT) {
    float u = noise[(size_t)b * V + si2[j]];
    float g = -logf(-logf(u));
    float kk = sv[j] / t + g;
    if (kk > key || (kk == key && si2[j] < kid)) { key = kk; kid = si2[j]; }
  }
  for (int off = 32; off; off >>= 1) {
    float ov = __shfl_down(key, off);
    int   oi = __shfl_down(kid, off);
    if (ov > key || (ov == key && oi < kid)) { key = ov; kid = oi; }
  }
  if ((tid & 63) == 0) { wv[tid >> 6] = key; wi[tid >> 6] = kid; }
  __syncthreads();
  if (tid == 0) {
    for (int w = 1; w < NW; w++)
      if (wv[w] > key || (wv[w] == key && wi[w] < kid)) { key = wv[w]; kid = wi[w]; }
    for (int s2 = 0; s2 < S; s2++) {
      float v = gbK[b * S + s2]; int ii = gbI[b * S + s2];
      if (v > key || (v == key && ii < kid)) { key = v; kid = ii; }
    }
    int smp = (kid == 0x7fffffff) ? 0 : kid;
    float lx = logits[(size_t)b * V + smp];
    float tlp = (lx - M) - logZ;
    unsigned loK = f2k(-3.0e38f);
    unsigned hiK = f2k(lx);
    while (hiK - loK > 1u) {
      unsigned mid = loK + ((hiK - loK) >> 1);
      float xm = k2f(mid);
      if (((xm - M) - logZ) >= tlp) hiK = mid; else loK = mid;
    }
    rowF[b * 16 + 9] = k2f(hiK);   // xcrit
    out[b] = (float)smp;
    out[Bn + (size_t)b * (K + 1)] = (float)smp;
    out[Bn + (size_t)Bn * (K + 1) + (size_t)b * (K + 1)] = tlp;
    out[Bn + 2 * (size_t)Bn * (K + 1) + b] = 0.0f;
  }
}

// K7 (mode2): rank = count(x >= xcrit) per slice -> atomic add
__global__ __launch_bounds__(NT) void k7(const float* __restrict__ logits,
    int V, int CS, const float* __restrict__ rowF, const int* __restrict__ rowI,
    float* __restrict__ out, int Bn, int K)
{
  const int s = blockIdx.x, b = blockIdx.y, tid = threadIdx.x;
  if (rowI[b * 16 + 1] != 2) return;
  const float xcrit = rowF[b * 16 + 9];
  const float* lrow = logits + (size_t)b * V;
  const int lo = s * CS, hi = min(V, lo + CS);
  __shared__ int wiv[NW];
  int rc = 0;
  const int vecEnd = lo + ((hi - lo) & ~3);
  const float4* l4 = reinterpret_cast<const float4*>(lrow);
  for (int i4 = (lo >> 2) + tid; i4 < (vecEnd >> 2); i4 += NT) {
    float4 x = l4[i4];
    rc += (x.x >= xcrit) + (x.y >= xcrit) + (x.z >= xcrit) + (x.w >= xcrit);
  }
  for (int i = vecEnd + tid; i < hi; i += NT) rc += (lrow[i] >= xcrit);
  for (int off = 32; off; off >>= 1) rc += __shfl_down(rc, off);
  if ((tid & 63) == 0) wiv[tid >> 6] = rc;
  __syncthreads();
  if (tid == 0) {
    int tot = 0;
    for (int w = 0; w < NW; w++) tot += wiv[w];
    atomicAdd(&out[Bn + 2 * (size_t)Bn * (K + 1) + b], (float)tot);
  }
}

extern "C" void kernel_launch(void* const* d_in, const int* in_sizes, int n_in,
                              void* d_out, int out_size, void* d_ws, size_t ws_size,
                              hipStream_t stream) {
  const float* logits = (const float*)d_in[0];
  const float* temp   = (const float*)d_in[1];
  const float* topp   = (const float*)d_in[2];
  const float* noise  = (const float*)d_in[3];
  const int*   topk   = (const int*)d_in[4];
  const int Bn = in_sizes[1];                         // 128
  const int V  = in_sizes[0] / Bn;                    // 128256
  const int K  = (out_size - 2 * Bn) / (2 * Bn) - 1;  // 20
  const int CS = (((V + S - 1) / S) + 3) & ~3;        // 8016

  char* w = (char*)d_ws;
  int*   histS  = (int*)w;    w += (size_t)Bn * S * NB * 4;
  float* massS  = (float*)w;  w += (size_t)Bn * S * NB * 4;
  float* scandV = (float*)w;  w += (size_t)Bn * S * SCAP * 4;
  int*   scandI = (int*)w;    w += (size_t)Bn * S * SCAP * 4;
  float* sMax   = (float*)w;  w += (size_t)Bn * S * 4;
  int*   sArg   = (int*)w;    w += (size_t)Bn * S * 4;
  float* sSum   = (float*)w;  w += (size_t)Bn * S * 4;
  int*   scnt   = (int*)w;    w += (size_t)Bn * S * 4;
  float* gbK    = (float*)w;  w += (size_t)Bn * S * 4;
  int*   gbI    = (int*)w;    w += (size_t)Bn * S * 4;
  float* l2V    = (float*)w;  w += (size_t)Bn * CAP2 * 4;
  int*   l2I    = (int*)w;    w += (size_t)Bn * CAP2 * 4;
  float* rowF   = (float*)w;  w += (size_t)Bn * 16 * 4;
  int*   rowI   = (int*)w;    w += (size_t)Bn * 16 * 4;
  int*   cnt2   = (int*)w;    w += (size_t)Bn * 4;

  dim3 gs(S, Bn);
  k1<<<gs, NT, 0, stream>>>(logits, V, CS, histS, sMax, sArg, sSum,
                            scandV, scandI, scnt);
  k2<<<Bn, NT, 0, stream>>>(temp, topp, topk, histS, sMax, sArg, sSum,
                            rowF, rowI, cnt2);
  k3<<<gs, NT, 0, stream>>>(logits, V, CS, rowF, rowI, massS);
  k4<<<Bn, NT, 0, stream>>>(logits, noise, V, K, scandV, scandI, scnt, massS,
                            rowF, rowI, (float*)d_out, Bn);
  k5<<<gs, NT, 0, stream>>>(logits, noise, V, CS, rowF, rowI, l2V, l2I, cnt2,
                            gbK, gbI);
  k6<<<Bn, NT, 0, stream>>>(logits, noise, V, K, l2V, l2I, cnt2, gbK, gbI,
                            rowF, rowI, (float*)d_out, Bn);
  k7<<<gs, NT, 0, stream>>>(logits, V, CS, rowF, rowI, (float*)d_out, Bn, K);
}

// Round 6
// 183.046 us; speedup vs baseline: 1.0974x; 1.0974x over previous
//
#include <hip/hip_runtime.h>
#include <float.h>
#include <math.h>

#define NT 256
#define NW (NT / 64)
#define S 16
#define NB 512
#define CAP1 1024
#define CAP2 2048
#define SCAP 512
#define LT 140
#define TGT 128
#define XMIN (-8.0f)
#define BINW (1.0f / 32.0f)
#define INVW (32.0f)
#define SEPS 1e-5f

__device__ __forceinline__ int binOf(float x) {
  int bn = (int)floorf((x - XMIN) * INVW);
  return bn < 0 ? 0 : (bn > NB - 1 ? NB - 1 : bn);
}
__device__ __forceinline__ unsigned f2k(float f) {
  unsigned u = __float_as_uint(f);
  return (u & 0x80000000u) ? ~u : (u | 0x80000000u);
}
__device__ __forceinline__ float k2f(unsigned k) {
  return __uint_as_float((k & 0x80000000u) ? (k ^ 0x80000000u) : ~k);
}

// K1: ONE pass over logits: wave-priv hist + slice max; then L2-hot re-read of
// own slice: exact slice sumexp, argmax-by-equality, collect slice-local top-LT.
__global__ __launch_bounds__(NT) void k1(const float* __restrict__ logits,
    int V, int CS, int* __restrict__ histS, float* __restrict__ sMax,
    int* __restrict__ sArg, float* __restrict__ sSum,
    float* __restrict__ scandV, int* __restrict__ scandI, int* __restrict__ scnt)
{
  const int s = blockIdx.x, b = blockIdx.y, tid = threadIdx.x;
  const int wid = tid >> 6;
  const float* lrow = logits + (size_t)b * V;
  const int lo = s * CS, hi = min(V, lo + CS);
  __shared__ int lh[4 * NB];
  __shared__ float wv[NW];
  __shared__ float shMax, shEdge;
  __shared__ int qn, shArg;
  __shared__ float qv[SCAP]; __shared__ int qi[SCAP];
  for (int j = tid; j < 4 * NB; j += NT) lh[j] = 0;
  if (tid == 0) { qn = 0; shArg = 0x7fffffff; }
  __syncthreads();

  const int vecEnd = lo + ((hi - lo) & ~3);
  const float4* l4 = reinterpret_cast<const float4*>(lrow);
  float bm = -FLT_MAX;
  int* lhw = &lh[wid * NB];
  for (int i4 = (lo >> 2) + tid; i4 < (vecEnd >> 2); i4 += NT) {
    float4 x = l4[i4];
    bm = fmaxf(bm, fmaxf(fmaxf(x.x, x.y), fmaxf(x.z, x.w)));
    atomicAdd(&lhw[binOf(x.x)], 1);
    atomicAdd(&lhw[binOf(x.y)], 1);
    atomicAdd(&lhw[binOf(x.z)], 1);
    atomicAdd(&lhw[binOf(x.w)], 1);
  }
  for (int i = vecEnd + tid; i < hi; i += NT) {
    float x = lrow[i];
    bm = fmaxf(bm, x);
    atomicAdd(&lhw[binOf(x)], 1);
  }
  for (int off = 32; off; off >>= 1) bm = fmaxf(bm, __shfl_down(bm, off));
  if ((tid & 63) == 0) wv[wid] = bm;
  __syncthreads();
  int* hslice = histS + ((size_t)b * S + s) * NB;
  for (int j = tid; j < NB; j += NT) {
    int tot = lh[j] + lh[NB + j] + lh[2 * NB + j] + lh[3 * NB + j];
    lh[j] = tot;
    hslice[j] = tot;
  }
  if (tid == 0) {
    float m = wv[0];
    for (int w = 1; w < NW; w++) m = fmaxf(m, wv[w]);
    shMax = m;
  }
  __syncthreads();
  if (tid == 0) {
    int cum = 0, jsel = 0;
    for (int j = NB - 1; j >= 0; j--) {
      cum += lh[j];
      if (cum >= LT) { jsel = j; break; }
    }
    shEdge = XMIN + jsel * BINW;
  }
  __syncthreads();
  const float Ml = shMax, edge = shEdge;
  float sum = 0.0f;
  for (int i4 = (lo >> 2) + tid; i4 < (vecEnd >> 2); i4 += NT) {
    float4 x = l4[i4];
    int base = i4 << 2;
    sum += expf(x.x - Ml) + expf(x.y - Ml) + expf(x.z - Ml) + expf(x.w - Ml);
    float xs[4] = {x.x, x.y, x.z, x.w};
    #pragma unroll
    for (int q = 0; q < 4; q++) {
      if (xs[q] >= edge) {
        int p2 = atomicAdd(&qn, 1);
        if (p2 < SCAP) { qv[p2] = xs[q]; qi[p2] = base + q; }
      }
      if (xs[q] == Ml) atomicMin(&shArg, base + q);
    }
  }
  for (int i = vecEnd + tid; i < hi; i += NT) {
    float x = lrow[i];
    sum += expf(x - Ml);
    if (x >= edge) {
      int p2 = atomicAdd(&qn, 1);
      if (p2 < SCAP) { qv[p2] = x; qi[p2] = i; }
    }
    if (x == Ml) atomicMin(&shArg, i);
  }
  for (int off = 32; off; off >>= 1) sum += __shfl_down(sum, off);
  if ((tid & 63) == 0) wv[wid] = sum;
  __syncthreads();
  if (tid == 0) {
    float ts = 0.0f;
    for (int w = 0; w < NW; w++) ts += wv[w];
    sSum[b * S + s] = ts;
    sMax[b * S + s] = shMax;
    sArg[b * S + s] = shArg;
    scnt[b * S + s] = min(qn, SCAP);
  }
  __syncthreads();
  int qc = min(qn, SCAP);
  float* cvs = scandV + ((size_t)b * S + s) * SCAP;
  int*   cis = scandI + ((size_t)b * S + s) * SCAP;
  for (int j = tid; j < qc; j += NT) { cvs[j] = qv[j]; cis[j] = qi[j]; }
}

// K2: sum slice hists -> global edge; M/gidx; exact logZ; mode; zero cnt2
__global__ __launch_bounds__(NT) void k2(const float* __restrict__ temp,
    const float* __restrict__ topp, const int* __restrict__ topk,
    const int* __restrict__ histS, const float* __restrict__ sMax,
    const int* __restrict__ sArg, const float* __restrict__ sSum,
    float* __restrict__ rowF, int* __restrict__ rowI, int* __restrict__ cnt2)
{
  const int b = blockIdx.x, tid = threadIdx.x;
  __shared__ int lc[NB];
  __shared__ float sMx[S], sSm[S]; __shared__ int sAg[S];
  for (int j = tid; j < NB; j += NT) {
    int tot = 0;
    for (int s2 = 0; s2 < S; s2++) tot += histS[((size_t)b * S + s2) * NB + j];
    lc[j] = tot;
  }
  if (tid < S) {
    sMx[tid] = sMax[b * S + tid];
    sSm[tid] = sSum[b * S + tid];
    sAg[tid] = sArg[b * S + tid];
  }
  __syncthreads();
  if (tid == 0) {
    float M = -FLT_MAX; int gi = 0x7fffffff;
    for (int s2 = 0; s2 < S; s2++) {
      float v = sMx[s2]; int ii = sAg[s2];
      if (v > M || (v == M && ii < gi)) { M = v; gi = ii; }
    }
    float Z = 0.0f;
    for (int s2 = 0; s2 < S; s2++) Z += sSm[s2] * expf(sMx[s2] - M);
    float logZ = logf(Z);
    int cum = 0, bsel = 0;
    for (int j = NB - 1; j >= 0; j--) {
      cum += lc[j];
      if (cum >= TGT) { bsel = j; break; }
    }
    int bc = (bsel >= 2) ? (bsel - 2) : 0;
    float t = temp[b]; float p = topp[b]; int k = topk[b];
    int mode = (t < SEPS) ? 0 : ((k >= 1) ? 1 : 2);
    rowF[b * 16 + 0] = M;
    rowF[b * 16 + 1] = logZ;
    rowF[b * 16 + 2] = XMIN + bc * BINW;
    rowF[b * 16 + 3] = (t >= SEPS) ? (M / t) : 0.0f;
    rowF[b * 16 + 4] = t;
    rowF[b * 16 + 5] = p;
    rowI[b * 16 + 0] = gi;
    rowI[b * 16 + 1] = mode;
    rowI[b * 16 + 2] = k;
    cnt2[b] = 0;
  }
}

// K3 (mode-2 rows only): mass histogram per slice (wave-privatized)
__global__ __launch_bounds__(NT) void k3(const float* __restrict__ logits,
    int V, int CS, const float* __restrict__ rowF, const int* __restrict__ rowI,
    float* __restrict__ massS)
{
  const int s = blockIdx.x, b = blockIdx.y, tid = threadIdx.x;
  if (rowI[b * 16 + 1] != 2) return;
  const int wid = tid >> 6;
  const float Ms = rowF[b * 16 + 3];
  const float t = rowF[b * 16 + 4];
  const float* lrow = logits + (size_t)b * V;
  const int lo = s * CS, hi = min(V, lo + CS);
  __shared__ float lm[4 * NB];
  for (int j = tid; j < 4 * NB; j += NT) lm[j] = 0.0f;
  __syncthreads();
  float* lmw = &lm[wid * NB];
  const int vecEnd = lo + ((hi - lo) & ~3);
  const float4* l4 = reinterpret_cast<const float4*>(lrow);
  for (int i4 = (lo >> 2) + tid; i4 < (vecEnd >> 2); i4 += NT) {
    float4 x = l4[i4];
    atomicAdd(&lmw[binOf(x.x)], expf(x.x / t - Ms));
    atomicAdd(&lmw[binOf(x.y)], expf(x.y / t - Ms));
    atomicAdd(&lmw[binOf(x.z)], expf(x.z / t - Ms));
    atomicAdd(&lmw[binOf(x.w)], expf(x.w / t - Ms));
  }
  for (int i = vecEnd + tid; i < hi; i += NT)
    atomicAdd(&lmw[binOf(lrow[i])], expf(lrow[i] / t - Ms));
  __syncthreads();
  float* mslice = massS + ((size_t)b * S + s) * NB;
  for (int j = tid; j < NB; j += NT)
    mslice[j] = lm[j] + lm[NB + j] + lm[2 * NB + j] + lm[3 * NB + j];
}

// K4: pool slice-candidates, filter by global edge, sort; top-K out;
// modes 0/1: sample + rank + finalize.  mode 2: mass scan -> boundary bin.
__global__ __launch_bounds__(NT) void k4(const float* __restrict__ logits,
    const float* __restrict__ noise, int V, int K,
    const float* __restrict__ scandV, const int* __restrict__ scandI,
    const int* __restrict__ scnt, const float* __restrict__ massS,
    float* __restrict__ rowF, int* __restrict__ rowI,
    float* __restrict__ out, int Bn)
{
  const int b = blockIdx.x, tid = threadIdx.x;
  __shared__ float cv[CAP1]; __shared__ int ci[CAP1];
  __shared__ float sv[CAP1]; __shared__ int si[CAP1];
  __shared__ float ev[CAP1];
  __shared__ float lmass[NB];
  __shared__ float fsum[NT];
  __shared__ float wv[NW]; __shared__ int wi[NW];
  __shared__ int shI[2]; __shared__ float shF[2];
  __shared__ int nn; __shared__ int scl[S];
  const float M = rowF[b * 16 + 0], logZ = rowF[b * 16 + 1], Ms = rowF[b * 16 + 3];
  const float t = rowF[b * 16 + 4], p = rowF[b * 16 + 5];
  const float edgeC = rowF[b * 16 + 2];
  const int mode = rowI[b * 16 + 1], k = rowI[b * 16 + 2], gidx = rowI[b * 16 + 0];
  if (tid == 0) nn = 0;
  if (tid < S) scl[tid] = scnt[b * S + tid];
  __syncthreads();
  for (int s2 = 0; s2 < S; s2++) {
    const float* cvs = scandV + ((size_t)b * S + s2) * SCAP;
    const int*   cis = scandI + ((size_t)b * S + s2) * SCAP;
    int c = scl[s2];
    for (int j = tid; j < c; j += NT) {
      float x = cvs[j];
      if (x >= edgeC) {
        int p2 = atomicAdd(&nn, 1);
        if (p2 < CAP1) { cv[p2] = x; ci[p2] = cis[j]; }
      }
    }
  }
  __syncthreads();
  const int n = min(nn, CAP1);
  for (int c = tid; c < n; c += NT) {
    float v = cv[c]; int id = ci[c]; int r = 0;
    for (int j = 0; j < n; j++) {
      float w = cv[j];
      r += (w > v) || (w == v && ci[j] < id);
    }
    sv[r] = v; si[r] = id;
  }
  __syncthreads();
  float* out_idx = out + Bn;
  float* out_lp  = out + Bn + (size_t)Bn * (K + 1);
  for (int j = tid; j < K && j < n; j += NT) {
    out_idx[(size_t)b * (K + 1) + 1 + j] = (float)si[j];
    out_lp [(size_t)b * (K + 1) + 1 + j] = (sv[j] - M) - logZ;
  }

  if (mode == 2) {
    for (int j = tid; j < NB; j += NT) {
      float tot = 0.0f;
      for (int s2 = 0; s2 < S; s2++) tot += massS[((size_t)b * S + s2) * NB + j];
      lmass[j] = tot;
    }
    __syncthreads();
    const int CH = NB / NT;
    float cs = 0.0f;
    for (int j = tid * CH; j < (tid + 1) * CH; j++) cs += lmass[j];
    fsum[tid] = cs;
    __syncthreads();
    if (tid == 0) {
      float Z2 = 0.0f;
      for (int c = 0; c < NT; c++) Z2 += fsum[c];
      float W = p * Z2;
      float ca = 0.0f; int c = NT - 1;
      for (; c >= 0; c--) {
        if (ca + fsum[c] >= W) break;
        ca += fsum[c];
      }
      if (c < 0) c = 0;
      int Bb = c * CH, found = -1;
      for (int j = c * CH + CH - 1; j >= c * CH; j--) {
        if (ca + lmass[j] >= W) { found = j; break; }
        ca += lmass[j];
      }
      if (found >= 0) Bb = found;
      rowF[b * 16 + 6] = W; rowF[b * 16 + 7] = ca; rowI[b * 16 + 3] = Bb;
    }
    return;
  }

  int smp; float lx;
  if (mode == 0) {
    smp = gidx; lx = M;
  } else {
    const int keff = min(k, n);
    for (int j = tid; j < keff; j += NT) ev[j] = expf(sv[j] / t - Ms);
    __syncthreads();
    if (tid == 0) {
      float Z = 0.0f;
      for (int j = 0; j < keff; j++) Z += ev[j];
      float W = p * Z;
      float cum = 0.0f; int m = 0;
      for (int j = 0; j < keff; j++) {
        if (cum < W) m++; else break;
        cum += ev[j];
      }
      shI[0] = m;
    }
    __syncthreads();
    const int m = shI[0];
    float key = -FLT_MAX; int kid = 0x7fffffff;
    for (int j = tid; j < m; j += NT) {
      float u = noise[(size_t)b * V + si[j]];
      float g = -logf(-logf(u));
      float kk = sv[j] / t + g;
      if (kk > key || (kk == key && si[j] < kid)) { key = kk; kid = si[j]; }
    }
    for (int off = 32; off; off >>= 1) {
      float ov = __shfl_down(key, off);
      int   oi = __shfl_down(kid, off);
      if (ov > key || (ov == key && oi < kid)) { key = ov; kid = oi; }
    }
    if ((tid & 63) == 0) { wv[tid >> 6] = key; wi[tid >> 6] = kid; }
    __syncthreads();
    if (tid == 0) {
      for (int w2 = 1; w2 < NW; w2++)
        if (wv[w2] > key || (wv[w2] == key && wi[w2] < kid)) { key = wv[w2]; kid = wi[w2]; }
      shI[1] = (kid == 0x7fffffff) ? 0 : kid;
    }
    __syncthreads();
    smp = shI[1];
    if (tid == 0) shF[0] = logits[(size_t)b * V + smp];
    __syncthreads();
    lx = shF[0];
  }
  const float tlp = (lx - M) - logZ;
  int rc = 0;
  for (int j = tid; j < n; j += NT) rc += (((sv[j] - M) - logZ) >= tlp) ? 1 : 0;
  for (int off = 32; off; off >>= 1) rc += __shfl_down(rc, off);
  __syncthreads();
  if ((tid & 63) == 0) wi[tid >> 6] = rc;
  __syncthreads();
  if (tid == 0) {
    int rank = 0;
    for (int w2 = 0; w2 < NW; w2++) rank += wi[w2];
    out[b] = (float)smp;
    out_idx[(size_t)b * (K + 1)] = (float)smp;
    out_lp [(size_t)b * (K + 1)] = tlp;
    out[Bn + 2 * (size_t)Bn * (K + 1) + b] = (float)rank;
  }
}

// K5 (mode2): collect boundary-bin elements + above-bin gumbel partials
__global__ __launch_bounds__(NT) void k5(const float* __restrict__ logits,
    const float* __restrict__ noise, int V, int CS,
    const float* __restrict__ rowF, const int* __restrict__ rowI,
    float* __restrict__ l2V, int* __restrict__ l2I, int* __restrict__ cnt2,
    float* __restrict__ gbK, int* __restrict__ gbI)
{
  const int s = blockIdx.x, b = blockIdx.y, tid = threadIdx.x;
  if (rowI[b * 16 + 1] != 2) return;
  const int Bb = rowI[b * 16 + 3];
  const float t = rowF[b * 16 + 4];
  const float* lrow = logits + (size_t)b * V;
  const float* nrow = noise + (size_t)b * V;
  const int lo = s * CS, hi = min(V, lo + CS);
  __shared__ int qn; __shared__ int sbase;
  __shared__ float qv[SCAP]; __shared__ int qi[SCAP];
  __shared__ float wv[NW]; __shared__ int wi[NW];
  if (tid == 0) qn = 0;
  __syncthreads();
  float key = -FLT_MAX; int kid = 0x7fffffff;
  for (int i = lo + tid; i < hi; i += NT) {
    float x = lrow[i];
    int bn = binOf(x);
    if (bn > Bb) {
      float g = -logf(-logf(nrow[i]));
      float kk = x / t + g;
      if (kk > key || (kk == key && i < kid)) { key = kk; kid = i; }
    } else if (bn == Bb) {
      int ppos = atomicAdd(&qn, 1);
      if (ppos < SCAP) { qv[ppos] = x; qi[ppos] = i; }
    }
  }
  for (int off = 32; off; off >>= 1) {
    float ov = __shfl_down(key, off);
    int   oi = __shfl_down(kid, off);
    if (ov > key || (ov == key && oi < kid)) { key = ov; kid = oi; }
  }
  if ((tid & 63) == 0) { wv[tid >> 6] = key; wi[tid >> 6] = kid; }
  __syncthreads();
  if (tid == 0) {
    for (int w = 1; w < NW; w++)
      if (wv[w] > key || (wv[w] == key && wi[w] < kid)) { key = wv[w]; kid = wi[w]; }
    gbK[b * S + s] = key; gbI[b * S + s] = kid;
  }
  int qc = min(qn, SCAP);
  if (tid == 0) sbase = atomicAdd(&cnt2[b], qc);
  __syncthreads();
  for (int j = tid; j < qc; j += NT) {
    int dst = sbase + j;
    if (dst < CAP2) { l2V[b * CAP2 + dst] = qv[j]; l2I[b * CAP2 + dst] = qi[j]; }
  }
}

// K6 (mode2): bitonic sort bin (desc by value, asc by idx), exact prefix,
// sample, bisect xcrit, finalize
__global__ __launch_bounds__(NT) void k6(const float* __restrict__ logits,
    const float* __restrict__ noise, int V, int K,
    const float* __restrict__ l2V, const int* __restrict__ l2I,
    const int* __restrict__ cnt2,
    const float* __restrict__ gbK, const int* __restrict__ gbI,
    float* __restrict__ rowF, const int* __restrict__ rowI,
    float* __restrict__ out, int Bn)
{
  const int b = blockIdx.x, tid = threadIdx.x;
  if (rowI[b * 16 + 1] != 2) return;
  __shared__ unsigned long long keys[CAP2];
  __shared__ float ev[CAP2];
  __shared__ float wv[NW]; __shared__ int wi[NW];
  __shared__ int shI[2];
  const int n2 = min(cnt2[b], CAP2);
  const float M = rowF[b * 16 + 0], logZ = rowF[b * 16 + 1], Ms = rowF[b * 16 + 3];
  const float t = rowF[b * 16 + 4];
  const float W = rowF[b * 16 + 6], CAv = rowF[b * 16 + 7];
  int n2p = 1;
  while (n2p < n2) n2p <<= 1;
  for (int j = tid; j < n2p; j += NT) {
    if (j < n2) {
      float v = l2V[b * CAP2 + j];
      unsigned id = (unsigned)l2I[b * CAP2 + j];
      keys[j] = ((unsigned long long)f2k(v) << 32) | (0xFFFFFFFFu - id);
    } else {
      keys[j] = 0ull;
    }
  }
  __syncthreads();
  for (int kk = 2; kk <= n2p; kk <<= 1) {
    for (int jj = kk >> 1; jj > 0; jj >>= 1) {
      for (int i = tid; i < n2p; i += NT) {
        int ixj = i ^ jj;
        if (ixj > i) {
          bool up = ((i & kk) == 0);           // descending blocks
          unsigned long long a = keys[i], b2 = keys[ixj];
          if (up ? (a < b2) : (a > b2)) { keys[i] = b2; keys[ixj] = a; }
        }
      }
      __syncthreads();
    }
  }
  for (int j = tid; j < n2; j += NT) {
    float v = k2f((unsigned)(keys[j] >> 32));
    ev[j] = expf(v / t - Ms);
  }
  __syncthreads();
  if (tid == 0) {
    float cum = CAv; int last = -1;
    for (int j = 0; j < n2; j++) {
      if (cum < W) last = j; else break;
      cum += ev[j];
    }
    shI[0] = last;
  }
  __syncthreads();
  const int last = shI[0];
  float key = -FLT_MAX; int kid = 0x7fffffff;
  for (int j = tid; j <= last; j += NT) {
    unsigned long long kv = keys[j];
    float v = k2f((unsigned)(kv >> 32));
    int id = (int)(0xFFFFFFFFu - (unsigned)(kv & 0xFFFFFFFFu));
    float u = noise[(size_t)b * V + id];
    float g = -logf(-logf(u));
    float kk = v / t + g;
    if (kk > key || (kk == key && id < kid)) { key = kk; kid = id; }
  }
  for (int off = 32; off; off >>= 1) {
    float ov = __shfl_down(key, off);
    int   oi = __shfl_down(kid, off);
    if (ov > key || (ov == key && oi < kid)) { key = ov; kid = oi; }
  }
  if ((tid & 63) == 0) { wv[tid >> 6] = key; wi[tid >> 6] = kid; }
  __syncthreads();
  if (tid == 0) {
    for (int w = 1; w < NW; w++)
      if (wv[w] > key || (wv[w] == key && wi[w] < kid)) { key = wv[w]; kid = wi[w]; }
    for (int s2 = 0; s2 < S; s2++) {
      float v = gbK[b * S + s2]; int ii = gbI[b * S + s2];
      if (v > key || (v == key && ii < kid)) { key = v; kid = ii; }
    }
    int smp = (kid == 0x7fffffff) ? 0 : kid;
    float lx = logits[(size_t)b * V + smp];
    float tlp = (lx - M) - logZ;
    unsigned loK = f2k(-3.0e38f);
    unsigned hiK = f2k(lx);
    while (hiK - loK > 1u) {
      unsigned mid = loK + ((hiK - loK) >> 1);
      float xm = k2f(mid);
      if (((xm - M) - logZ) >= tlp) hiK = mid; else loK = mid;
    }
    rowF[b * 16 + 9] = k2f(hiK);   // xcrit
    out[b] = (float)smp;
    out[Bn + (size_t)b * (K + 1)] = (float)smp;
    out[Bn + (size_t)Bn * (K + 1) + (size_t)b * (K + 1)] = tlp;
    out[Bn + 2 * (size_t)Bn * (K + 1) + b] = 0.0f;
  }
}

// K7 (mode2): rank = count(x >= xcrit) per slice -> atomic add
__global__ __launch_bounds__(NT) void k7(const float* __restrict__ logits,
    int V, int CS, const float* __restrict__ rowF, const int* __restrict__ rowI,
    float* __restrict__ out, int Bn, int K)
{
  const int s = blockIdx.x, b = blockIdx.y, tid = threadIdx.x;
  if (rowI[b * 16 + 1] != 2) return;
  const float xcrit = rowF[b * 16 + 9];
  const float* lrow = logits + (size_t)b * V;
  const int lo = s * CS, hi = min(V, lo + CS);
  __shared__ int wiv[NW];
  int rc = 0;
  const int vecEnd = lo + ((hi - lo) & ~3);
  const float4* l4 = reinterpret_cast<const float4*>(lrow);
  for (int i4 = (lo >> 2) + tid; i4 < (vecEnd >> 2); i4 += NT) {
    float4 x = l4[i4];
    rc += (x.x >= xcrit) + (x.y >= xcrit) + (x.z >= xcrit) + (x.w >= xcrit);
  }
  for (int i = vecEnd + tid; i < hi; i += NT) rc += (lrow[i] >= xcrit);
  for (int off = 32; off; off >>= 1) rc += __shfl_down(rc, off);
  if ((tid & 63) == 0) wiv[tid >> 6] = rc;
  __syncthreads();
  if (tid == 0) {
    int tot = 0;
    for (int w = 0; w < NW; w++) tot += wiv[w];
    atomicAdd(&out[Bn + 2 * (size_t)Bn * (K + 1) + b], (float)tot);
  }
}

extern "C" void kernel_launch(void* const* d_in, const int* in_sizes, int n_in,
                              void* d_out, int out_size, void* d_ws, size_t ws_size,
                              hipStream_t stream) {
  const float* logits = (const float*)d_in[0];
  const float* temp   = (const float*)d_in[1];
  const float* topp   = (const float*)d_in[2];
  const float* noise  = (const float*)d_in[3];
  const int*   topk   = (const int*)d_in[4];
  const int Bn = in_sizes[1];                         // 128
  const int V  = in_sizes[0] / Bn;                    // 128256
  const int K  = (out_size - 2 * Bn) / (2 * Bn) - 1;  // 20
  const int CS = (((V + S - 1) / S) + 3) & ~3;        // 8016

  char* w = (char*)d_ws;
  int*   histS  = (int*)w;    w += (size_t)Bn * S * NB * 4;
  float* massS  = (float*)w;  w += (size_t)Bn * S * NB * 4;
  float* scandV = (float*)w;  w += (size_t)Bn * S * SCAP * 4;
  int*   scandI = (int*)w;    w += (size_t)Bn * S * SCAP * 4;
  float* sMax   = (float*)w;  w += (size_t)Bn * S * 4;
  int*   sArg   = (int*)w;    w += (size_t)Bn * S * 4;
  float* sSum   = (float*)w;  w += (size_t)Bn * S * 4;
  int*   scnt   = (int*)w;    w += (size_t)Bn * S * 4;
  float* gbK    = (float*)w;  w += (size_t)Bn * S * 4;
  int*   gbI    = (int*)w;    w += (size_t)Bn * S * 4;
  float* l2V    = (float*)w;  w += (size_t)Bn * CAP2 * 4;
  int*   l2I    = (int*)w;    w += (size_t)Bn * CAP2 * 4;
  float* rowF   = (float*)w;  w += (size_t)Bn * 16 * 4;
  int*   rowI   = (int*)w;    w += (size_t)Bn * 16 * 4;
  int*   cnt2   = (int*)w;    w += (size_t)Bn * 4;

  dim3 gs(S, Bn);
  k1<<<gs, NT, 0, stream>>>(logits, V, CS, histS, sMax, sArg, sSum,
                            scandV, scandI, scnt);
  k2<<<Bn, NT, 0, stream>>>(temp, topp, topk, histS, sMax, sArg, sSum,
                            rowF, rowI, cnt2);
  k3<<<gs, NT, 0, stream>>>(logits, V, CS, rowF, rowI, massS);
  k4<<<Bn, NT, 0, stream>>>(logits, noise, V, K, scandV, scandI, scnt, massS,
                            rowF, rowI, (float*)d_out, Bn);
  k5<<<gs, NT, 0, stream>>>(logits, noise, V, CS, rowF, rowI, l2V, l2I, cnt2,
                            gbK, gbI);
  k6<<<Bn, NT, 0, stream>>>(logits, noise, V, K, l2V, l2I, cnt2, gbK, gbI,
                            rowF, rowI, (float*)d_out, Bn);
  k7<<<gs, NT, 0, stream>>>(logits, V, CS, rowF, rowI, (float*)d_out, Bn, K);
}

// Round 7
// 136.038 us; speedup vs baseline: 1.4766x; 1.3456x over previous
//
#include <hip/hip_runtime.h>
#include <float.h>
#include <math.h>

#define NT 256
#define NW (NT / 64)
#define S 16
#define NB 512
#define CAP1 1024
#define CAP2 2048
#define SCAP 512
#define LT 140
#define TGT 128
#define XMIN (-8.0f)
#define BINW (1.0f / 32.0f)
#define INVW (32.0f)
#define NSUB 1024
#define SUBCH (NSUB / NT)
#define SUBINV ((float)NSUB / BINW)
#define BCAP 512
#define SEPS 1e-5f

__device__ __forceinline__ int binOf(float x) {
  int bn = (int)floorf((x - XMIN) * INVW);
  return bn < 0 ? 0 : (bn > NB - 1 ? NB - 1 : bn);
}
__device__ __forceinline__ unsigned f2k(float f) {
  unsigned u = __float_as_uint(f);
  return (u & 0x80000000u) ? ~u : (u | 0x80000000u);
}
__device__ __forceinline__ float k2f(unsigned k) {
  return __uint_as_float((k & 0x80000000u) ? (k ^ 0x80000000u) : ~k);
}

// K1: ONE pass over logits: wave-priv hist + slice max; then L2-hot re-read of
// own slice: exact slice sumexp, argmax-by-equality, collect slice-local top-LT.
__global__ __launch_bounds__(NT) void k1(const float* __restrict__ logits,
    int V, int CS, int* __restrict__ histS, float* __restrict__ sMax,
    int* __restrict__ sArg, float* __restrict__ sSum,
    float* __restrict__ scandV, int* __restrict__ scandI, int* __restrict__ scnt)
{
  const int s = blockIdx.x, b = blockIdx.y, tid = threadIdx.x;
  const int wid = tid >> 6;
  const float* lrow = logits + (size_t)b * V;
  const int lo = s * CS, hi = min(V, lo + CS);
  __shared__ int lh[4 * NB];
  __shared__ float wv[NW];
  __shared__ float shMax, shEdge;
  __shared__ int qn, shArg;
  __shared__ float qv[SCAP]; __shared__ int qi[SCAP];
  for (int j = tid; j < 4 * NB; j += NT) lh[j] = 0;
  if (tid == 0) { qn = 0; shArg = 0x7fffffff; }
  __syncthreads();

  const int vecEnd = lo + ((hi - lo) & ~3);
  const float4* l4 = reinterpret_cast<const float4*>(lrow);
  float bm = -FLT_MAX;
  int* lhw = &lh[wid * NB];
  for (int i4 = (lo >> 2) + tid; i4 < (vecEnd >> 2); i4 += NT) {
    float4 x = l4[i4];
    bm = fmaxf(bm, fmaxf(fmaxf(x.x, x.y), fmaxf(x.z, x.w)));
    atomicAdd(&lhw[binOf(x.x)], 1);
    atomicAdd(&lhw[binOf(x.y)], 1);
    atomicAdd(&lhw[binOf(x.z)], 1);
    atomicAdd(&lhw[binOf(x.w)], 1);
  }
  for (int i = vecEnd + tid; i < hi; i += NT) {
    float x = lrow[i];
    bm = fmaxf(bm, x);
    atomicAdd(&lhw[binOf(x)], 1);
  }
  for (int off = 32; off; off >>= 1) bm = fmaxf(bm, __shfl_down(bm, off));
  if ((tid & 63) == 0) wv[wid] = bm;
  __syncthreads();
  int* hslice = histS + ((size_t)b * S + s) * NB;
  for (int j = tid; j < NB; j += NT) {
    int tot = lh[j] + lh[NB + j] + lh[2 * NB + j] + lh[3 * NB + j];
    lh[j] = tot;
    hslice[j] = tot;
  }
  if (tid == 0) {
    float m = wv[0];
    for (int w = 1; w < NW; w++) m = fmaxf(m, wv[w]);
    shMax = m;
  }
  __syncthreads();
  if (tid == 0) {
    int cum = 0, jsel = 0;
    for (int j = NB - 1; j >= 0; j--) {
      cum += lh[j];
      if (cum >= LT) { jsel = j; break; }
    }
    shEdge = XMIN + jsel * BINW;
  }
  __syncthreads();
  const float Ml = shMax, edge = shEdge;
  float sum = 0.0f;
  for (int i4 = (lo >> 2) + tid; i4 < (vecEnd >> 2); i4 += NT) {
    float4 x = l4[i4];
    int base = i4 << 2;
    sum += expf(x.x - Ml) + expf(x.y - Ml) + expf(x.z - Ml) + expf(x.w - Ml);
    float xs[4] = {x.x, x.y, x.z, x.w};
    #pragma unroll
    for (int q = 0; q < 4; q++) {
      if (xs[q] >= edge) {
        int p2 = atomicAdd(&qn, 1);
        if (p2 < SCAP) { qv[p2] = xs[q]; qi[p2] = base + q; }
      }
      if (xs[q] == Ml) atomicMin(&shArg, base + q);
    }
  }
  for (int i = vecEnd + tid; i < hi; i += NT) {
    float x = lrow[i];
    sum += expf(x - Ml);
    if (x >= edge) {
      int p2 = atomicAdd(&qn, 1);
      if (p2 < SCAP) { qv[p2] = x; qi[p2] = i; }
    }
    if (x == Ml) atomicMin(&shArg, i);
  }
  for (int off = 32; off; off >>= 1) sum += __shfl_down(sum, off);
  if ((tid & 63) == 0) wv[wid] = sum;
  __syncthreads();
  if (tid == 0) {
    float ts = 0.0f;
    for (int w = 0; w < NW; w++) ts += wv[w];
    sSum[b * S + s] = ts;
    sMax[b * S + s] = shMax;
    sArg[b * S + s] = shArg;
    scnt[b * S + s] = min(qn, SCAP);
  }
  __syncthreads();
  int qc = min(qn, SCAP);
  float* cvs = scandV + ((size_t)b * S + s) * SCAP;
  int*   cis = scandI + ((size_t)b * S + s) * SCAP;
  for (int j = tid; j < qc; j += NT) { cvs[j] = qv[j]; cis[j] = qi[j]; }
}

// K2: sum slice hists -> global edge; M/gidx; exact logZ; mode; zero cnt2
__global__ __launch_bounds__(NT) void k2(const float* __restrict__ temp,
    const float* __restrict__ topp, const int* __restrict__ topk,
    const int* __restrict__ histS, const float* __restrict__ sMax,
    const int* __restrict__ sArg, const float* __restrict__ sSum,
    float* __restrict__ rowF, int* __restrict__ rowI, int* __restrict__ cnt2)
{
  const int b = blockIdx.x, tid = threadIdx.x;
  __shared__ int lc[NB];
  __shared__ float sMx[S], sSm[S]; __shared__ int sAg[S];
  for (int j = tid; j < NB; j += NT) {
    int tot = 0;
    for (int s2 = 0; s2 < S; s2++) tot += histS[((size_t)b * S + s2) * NB + j];
    lc[j] = tot;
  }
  if (tid < S) {
    sMx[tid] = sMax[b * S + tid];
    sSm[tid] = sSum[b * S + tid];
    sAg[tid] = sArg[b * S + tid];
  }
  __syncthreads();
  if (tid == 0) {
    float M = -FLT_MAX; int gi = 0x7fffffff;
    for (int s2 = 0; s2 < S; s2++) {
      float v = sMx[s2]; int ii = sAg[s2];
      if (v > M || (v == M && ii < gi)) { M = v; gi = ii; }
    }
    float Z = 0.0f;
    for (int s2 = 0; s2 < S; s2++) Z += sSm[s2] * expf(sMx[s2] - M);
    float logZ = logf(Z);
    int cum = 0, bsel = 0;
    for (int j = NB - 1; j >= 0; j--) {
      cum += lc[j];
      if (cum >= TGT) { bsel = j; break; }
    }
    int bc = (bsel >= 2) ? (bsel - 2) : 0;
    float t = temp[b]; float p = topp[b]; int k = topk[b];
    int mode = (t < SEPS) ? 0 : ((k >= 1) ? 1 : 2);
    rowF[b * 16 + 0] = M;
    rowF[b * 16 + 1] = logZ;
    rowF[b * 16 + 2] = XMIN + bc * BINW;
    rowF[b * 16 + 3] = (t >= SEPS) ? (M / t) : 0.0f;
    rowF[b * 16 + 4] = t;
    rowF[b * 16 + 5] = p;
    rowI[b * 16 + 0] = gi;
    rowI[b * 16 + 1] = mode;
    rowI[b * 16 + 2] = k;
    cnt2[b] = 0;
  }
}

// K3 (mode-2 rows only): mass histogram per slice (wave-privatized)
__global__ __launch_bounds__(NT) void k3(const float* __restrict__ logits,
    int V, int CS, const float* __restrict__ rowF, const int* __restrict__ rowI,
    float* __restrict__ massS)
{
  const int s = blockIdx.x, b = blockIdx.y, tid = threadIdx.x;
  if (rowI[b * 16 + 1] != 2) return;
  const int wid = tid >> 6;
  const float Ms = rowF[b * 16 + 3];
  const float t = rowF[b * 16 + 4];
  const float* lrow = logits + (size_t)b * V;
  const int lo = s * CS, hi = min(V, lo + CS);
  __shared__ float lm[4 * NB];
  for (int j = tid; j < 4 * NB; j += NT) lm[j] = 0.0f;
  __syncthreads();
  float* lmw = &lm[wid * NB];
  const int vecEnd = lo + ((hi - lo) & ~3);
  const float4* l4 = reinterpret_cast<const float4*>(lrow);
  for (int i4 = (lo >> 2) + tid; i4 < (vecEnd >> 2); i4 += NT) {
    float4 x = l4[i4];
    atomicAdd(&lmw[binOf(x.x)], expf(x.x / t - Ms));
    atomicAdd(&lmw[binOf(x.y)], expf(x.y / t - Ms));
    atomicAdd(&lmw[binOf(x.z)], expf(x.z / t - Ms));
    atomicAdd(&lmw[binOf(x.w)], expf(x.w / t - Ms));
  }
  for (int i = vecEnd + tid; i < hi; i += NT)
    atomicAdd(&lmw[binOf(lrow[i])], expf(lrow[i] / t - Ms));
  __syncthreads();
  float* mslice = massS + ((size_t)b * S + s) * NB;
  for (int j = tid; j < NB; j += NT)
    mslice[j] = lm[j] + lm[NB + j] + lm[2 * NB + j] + lm[3 * NB + j];
}

// K4: pool slice-candidates, filter by global edge, sort; top-K out;
// modes 0/1: sample + rank + finalize.  mode 2: mass scan -> boundary bin.
__global__ __launch_bounds__(NT) void k4(const float* __restrict__ logits,
    const float* __restrict__ noise, int V, int K,
    const float* __restrict__ scandV, const int* __restrict__ scandI,
    const int* __restrict__ scnt, const float* __restrict__ massS,
    float* __restrict__ rowF, int* __restrict__ rowI,
    float* __restrict__ out, int Bn)
{
  const int b = blockIdx.x, tid = threadIdx.x;
  __shared__ float cv[CAP1]; __shared__ int ci[CAP1];
  __shared__ float sv[CAP1]; __shared__ int si[CAP1];
  __shared__ float ev[CAP1];
  __shared__ float lmass[NB];
  __shared__ float fsum[NT];
  __shared__ float wv[NW]; __shared__ int wi[NW];
  __shared__ int shI[2]; __shared__ float shF[2];
  __shared__ int nn; __shared__ int scl[S];
  const float M = rowF[b * 16 + 0], logZ = rowF[b * 16 + 1], Ms = rowF[b * 16 + 3];
  const float t = rowF[b * 16 + 4], p = rowF[b * 16 + 5];
  const float edgeC = rowF[b * 16 + 2];
  const int mode = rowI[b * 16 + 1], k = rowI[b * 16 + 2], gidx = rowI[b * 16 + 0];
  if (tid == 0) nn = 0;
  if (tid < S) scl[tid] = scnt[b * S + tid];
  __syncthreads();
  for (int s2 = 0; s2 < S; s2++) {
    const float* cvs = scandV + ((size_t)b * S + s2) * SCAP;
    const int*   cis = scandI + ((size_t)b * S + s2) * SCAP;
    int c = scl[s2];
    for (int j = tid; j < c; j += NT) {
      float x = cvs[j];
      if (x >= edgeC) {
        int p2 = atomicAdd(&nn, 1);
        if (p2 < CAP1) { cv[p2] = x; ci[p2] = cis[j]; }
      }
    }
  }
  __syncthreads();
  const int n = min(nn, CAP1);
  for (int c = tid; c < n; c += NT) {
    float v = cv[c]; int id = ci[c]; int r = 0;
    for (int j = 0; j < n; j++) {
      float w = cv[j];
      r += (w > v) || (w == v && ci[j] < id);
    }
    sv[r] = v; si[r] = id;
  }
  __syncthreads();
  float* out_idx = out + Bn;
  float* out_lp  = out + Bn + (size_t)Bn * (K + 1);
  for (int j = tid; j < K && j < n; j += NT) {
    out_idx[(size_t)b * (K + 1) + 1 + j] = (float)si[j];
    out_lp [(size_t)b * (K + 1) + 1 + j] = (sv[j] - M) - logZ;
  }

  if (mode == 2) {
    for (int j = tid; j < NB; j += NT) {
      float tot = 0.0f;
      for (int s2 = 0; s2 < S; s2++) tot += massS[((size_t)b * S + s2) * NB + j];
      lmass[j] = tot;
    }
    __syncthreads();
    const int CH = NB / NT;
    float cs = 0.0f;
    for (int j = tid * CH; j < (tid + 1) * CH; j++) cs += lmass[j];
    fsum[tid] = cs;
    __syncthreads();
    if (tid == 0) {
      float Z2 = 0.0f;
      for (int c = 0; c < NT; c++) Z2 += fsum[c];
      float W = p * Z2;
      float ca = 0.0f; int c = NT - 1;
      for (; c >= 0; c--) {
        if (ca + fsum[c] >= W) break;
        ca += fsum[c];
      }
      if (c < 0) c = 0;
      int Bb = c * CH, found = -1;
      for (int j = c * CH + CH - 1; j >= c * CH; j--) {
        if (ca + lmass[j] >= W) { found = j; break; }
        ca += lmass[j];
      }
      if (found >= 0) Bb = found;
      rowF[b * 16 + 6] = W; rowF[b * 16 + 7] = ca; rowI[b * 16 + 3] = Bb;
    }
    return;
  }

  int smp; float lx;
  if (mode == 0) {
    smp = gidx; lx = M;
  } else {
    const int keff = min(k, n);
    for (int j = tid; j < keff; j += NT) ev[j] = expf(sv[j] / t - Ms);
    __syncthreads();
    if (tid == 0) {
      float Z = 0.0f;
      for (int j = 0; j < keff; j++) Z += ev[j];
      float W = p * Z;
      float cum = 0.0f; int m = 0;
      for (int j = 0; j < keff; j++) {
        if (cum < W) m++; else break;
        cum += ev[j];
      }
      shI[0] = m;
    }
    __syncthreads();
    const int m = shI[0];
    float key = -FLT_MAX; int kid = 0x7fffffff;
    for (int j = tid; j < m; j += NT) {
      float u = noise[(size_t)b * V + si[j]];
      float g = -logf(-logf(u));
      float kk = sv[j] / t + g;
      if (kk > key || (kk == key && si[j] < kid)) { key = kk; kid = si[j]; }
    }
    for (int off = 32; off; off >>= 1) {
      float ov = __shfl_down(key, off);
      int   oi = __shfl_down(kid, off);
      if (ov > key || (ov == key && oi < kid)) { key = ov; kid = oi; }
    }
    if ((tid & 63) == 0) { wv[tid >> 6] = key; wi[tid >> 6] = kid; }
    __syncthreads();
    if (tid == 0) {
      for (int w2 = 1; w2 < NW; w2++)
        if (wv[w2] > key || (wv[w2] == key && wi[w2] < kid)) { key = wv[w2]; kid = wi[w2]; }
      shI[1] = (kid == 0x7fffffff) ? 0 : kid;
    }
    __syncthreads();
    smp = shI[1];
    if (tid == 0) shF[0] = logits[(size_t)b * V + smp];
    __syncthreads();
    lx = shF[0];
  }
  const float tlp = (lx - M) - logZ;
  int rc = 0;
  for (int j = tid; j < n; j += NT) rc += (((sv[j] - M) - logZ) >= tlp) ? 1 : 0;
  for (int off = 32; off; off >>= 1) rc += __shfl_down(rc, off);
  __syncthreads();
  if ((tid & 63) == 0) wi[tid >> 6] = rc;
  __syncthreads();
  if (tid == 0) {
    int rank = 0;
    for (int w2 = 0; w2 < NW; w2++) rank += wi[w2];
    out[b] = (float)smp;
    out_idx[(size_t)b * (K + 1)] = (float)smp;
    out_lp [(size_t)b * (K + 1)] = tlp;
    out[Bn + 2 * (size_t)Bn * (K + 1) + b] = (float)rank;
  }
}

// K5 (mode2): collect boundary-bin elements + above-bin gumbel partials
__global__ __launch_bounds__(NT) void k5(const float* __restrict__ logits,
    const float* __restrict__ noise, int V, int CS,
    const float* __restrict__ rowF, const int* __restrict__ rowI,
    float* __restrict__ l2V, int* __restrict__ l2I, int* __restrict__ cnt2,
    float* __restrict__ gbK, int* __restrict__ gbI)
{
  const int s = blockIdx.x, b = blockIdx.y, tid = threadIdx.x;
  if (rowI[b * 16 + 1] != 2) return;
  const int Bb = rowI[b * 16 + 3];
  const float t = rowF[b * 16 + 4];
  const float* lrow = logits + (size_t)b * V;
  const float* nrow = noise + (size_t)b * V;
  const int lo = s * CS, hi = min(V, lo + CS);
  __shared__ int qn; __shared__ int sbase;
  __shared__ float qv[SCAP]; __shared__ int qi[SCAP];
  __shared__ float wv[NW]; __shared__ int wi[NW];
  if (tid == 0) qn = 0;
  __syncthreads();
  float key = -FLT_MAX; int kid = 0x7fffffff;
  for (int i = lo + tid; i < hi; i += NT) {
    float x = lrow[i];
    int bn = binOf(x);
    if (bn > Bb) {
      float g = -logf(-logf(nrow[i]));
      float kk = x / t + g;
      if (kk > key || (kk == key && i < kid)) { key = kk; kid = i; }
    } else if (bn == Bb) {
      int ppos = atomicAdd(&qn, 1);
      if (ppos < SCAP) { qv[ppos] = x; qi[ppos] = i; }
    }
  }
  for (int off = 32; off; off >>= 1) {
    float ov = __shfl_down(key, off);
    int   oi = __shfl_down(kid, off);
    if (ov > key || (ov == key && oi < kid)) { key = ov; kid = oi; }
  }
  if ((tid & 63) == 0) { wv[tid >> 6] = key; wi[tid >> 6] = kid; }
  __syncthreads();
  if (tid == 0) {
    for (int w = 1; w < NW; w++)
      if (wv[w] > key || (wv[w] == key && wi[w] < kid)) { key = wv[w]; kid = wi[w]; }
    gbK[b * S + s] = key; gbI[b * S + s] = kid;
  }
  int qc = min(qn, SCAP);
  if (tid == 0) sbase = atomicAdd(&cnt2[b], qc);
  __syncthreads();
  for (int j = tid; j < qc; j += NT) {
    int dst = sbase + j;
    if (dst < CAP2) { l2V[b * CAP2 + dst] = qv[j]; l2I[b * CAP2 + dst] = qi[j]; }
  }
}

// K6 (mode2): sub-bin histogram refinement (no sort), exact boundary handling,
// sample, bisect xcrit, finalize
__global__ __launch_bounds__(NT) void k6(const float* __restrict__ logits,
    const float* __restrict__ noise, int V, int K,
    const float* __restrict__ l2V, const int* __restrict__ l2I,
    const int* __restrict__ cnt2,
    const float* __restrict__ gbK, const int* __restrict__ gbI,
    float* __restrict__ rowF, const int* __restrict__ rowI,
    float* __restrict__ out, int Bn)
{
  const int b = blockIdx.x, tid = threadIdx.x;
  if (rowI[b * 16 + 1] != 2) return;
  __shared__ float vals[CAP2]; __shared__ int idxs[CAP2]; __shared__ float evs[CAP2];
  __shared__ float subM[NSUB];
  __shared__ float fsum[NT];
  __shared__ int borderU[BCAP]; __shared__ int border[BCAP];
  __shared__ float wv[NW]; __shared__ int wi[NW];
  __shared__ int shBs, shLast, shBcnt;
  __shared__ float shCa;
  const int n2 = min(cnt2[b], CAP2);
  const float M = rowF[b * 16 + 0], logZ = rowF[b * 16 + 1], Ms = rowF[b * 16 + 3];
  const float t = rowF[b * 16 + 4];
  const float W = rowF[b * 16 + 6], CAv = rowF[b * 16 + 7];
  const int Bb = rowI[b * 16 + 3];
  const float binLo = XMIN + Bb * BINW;
  for (int j = tid; j < NSUB; j += NT) subM[j] = 0.0f;
  if (tid == 0) shBcnt = 0;
  __syncthreads();
  for (int j = tid; j < n2; j += NT) {
    float v = l2V[b * CAP2 + j]; int id = l2I[b * CAP2 + j];
    vals[j] = v; idxs[j] = id;
    float e = expf(v / t - Ms); evs[j] = e;
    int sb = (int)floorf((v - binLo) * SUBINV);
    sb = sb < 0 ? 0 : (sb > NSUB - 1 ? NSUB - 1 : sb);
    atomicAdd(&subM[sb], e);
  }
  __syncthreads();
  float cs = 0.0f;
  for (int j = tid * SUBCH; j < (tid + 1) * SUBCH; j++) cs += subM[j];
  fsum[tid] = cs;
  __syncthreads();
  if (tid == 0) {
    float cum = CAv; int Bs = -1; int c;
    for (c = NT - 1; c >= 0; c--) {
      if (cum + fsum[c] >= W) break;
      cum += fsum[c];
    }
    if (c >= 0) {
      for (int j = c * SUBCH + SUBCH - 1; j >= 0; j--) {
        if (cum + subM[j] >= W) { Bs = j; break; }
        cum += subM[j];
      }
    }
    shBs = Bs; shCa = cum;
  }
  __syncthreads();
  const int Bs = shBs;
  if (Bs >= 0) {
    for (int j = tid; j < n2; j += NT) {
      int sb = (int)floorf((vals[j] - binLo) * SUBINV);
      sb = sb < 0 ? 0 : (sb > NSUB - 1 ? NSUB - 1 : sb);
      if (sb == Bs) {
        int p2 = atomicAdd(&shBcnt, 1);
        if (p2 < BCAP) borderU[p2] = j;
      }
    }
  }
  __syncthreads();
  const int m = min(shBcnt, BCAP);
  for (int q = tid; q < m; q += NT) {
    int j = borderU[q];
    float v = vals[j]; int id = idxs[j]; int r = 0;
    for (int q2 = 0; q2 < m; q2++) {
      int j2 = borderU[q2];
      float w2 = vals[j2]; int id2 = idxs[j2];
      r += (w2 > v) || (w2 == v && id2 < id);
    }
    border[r] = j;
  }
  __syncthreads();
  if (tid == 0) {
    float cum = shCa; int lastq = -1;
    for (int q = 0; q < m; q++) {
      if (cum < W) lastq = q; else break;
      cum += evs[border[q]];
    }
    shLast = lastq;
  }
  __syncthreads();
  const int lastq = shLast;
  float key = -FLT_MAX; int kid = 0x7fffffff;
  for (int j = tid; j < n2; j += NT) {
    int sb = (int)floorf((vals[j] - binLo) * SUBINV);
    sb = sb < 0 ? 0 : (sb > NSUB - 1 ? NSUB - 1 : sb);
    if (sb > Bs) {
      float u = noise[(size_t)b * V + idxs[j]];
      float g = -logf(-logf(u));
      float kk = vals[j] / t + g;
      if (kk > key || (kk == key && idxs[j] < kid)) { key = kk; kid = idxs[j]; }
    }
  }
  for (int q = tid; q <= lastq; q += NT) {
    int j = border[q];
    float u = noise[(size_t)b * V + idxs[j]];
    float g = -logf(-logf(u));
    float kk = vals[j] / t + g;
    if (kk > key || (kk == key && idxs[j] < kid)) { key = kk; kid = idxs[j]; }
  }
  for (int off = 32; off; off >>= 1) {
    float ov = __shfl_down(key, off);
    int   oi = __shfl_down(kid, off);
    if (ov > key || (ov == key && oi < kid)) { key = ov; kid = oi; }
  }
  if ((tid & 63) == 0) { wv[tid >> 6] = key; wi[tid >> 6] = kid; }
  __syncthreads();
  if (tid == 0) {
    for (int w = 1; w < NW; w++)
      if (wv[w] > key || (wv[w] == key && wi[w] < kid)) { key = wv[w]; kid = wi[w]; }
    for (int s2 = 0; s2 < S; s2++) {
      float v = gbK[b * S + s2]; int ii = gbI[b * S + s2];
      if (v > key || (v == key && ii < kid)) { key = v; kid = ii; }
    }
    int smp = (kid == 0x7fffffff) ? 0 : kid;
    float lx = logits[(size_t)b * V + smp];
    float tlp = (lx - M) - logZ;
    unsigned loK = f2k(-3.0e38f);
    unsigned hiK = f2k(lx);
    while (hiK - loK > 1u) {
      unsigned mid = loK + ((hiK - loK) >> 1);
      float xm = k2f(mid);
      if (((xm - M) - logZ) >= tlp) hiK = mid; else loK = mid;
    }
    rowF[b * 16 + 9] = k2f(hiK);   // xcrit
    out[b] = (float)smp;
    out[Bn + (size_t)b * (K + 1)] = (float)smp;
    out[Bn + (size_t)Bn * (K + 1) + (size_t)b * (K + 1)] = tlp;
    out[Bn + 2 * (size_t)Bn * (K + 1) + b] = 0.0f;
  }
}

// K7 (mode2): rank = count(x >= xcrit) per slice -> atomic add
__global__ __launch_bounds__(NT) void k7(const float* __restrict__ logits,
    int V, int CS, const float* __restrict__ rowF, const int* __restrict__ rowI,
    float* __restrict__ out, int Bn, int K)
{
  const int s = blockIdx.x, b = blockIdx.y, tid = threadIdx.x;
  if (rowI[b * 16 + 1] != 2) return;
  const float xcrit = rowF[b * 16 + 9];
  const float* lrow = logits + (size_t)b * V;
  const int lo = s * CS, hi = min(V, lo + CS);
  __shared__ int wiv[NW];
  int rc = 0;
  const int vecEnd = lo + ((hi - lo) & ~3);
  const float4* l4 = reinterpret_cast<const float4*>(lrow);
  for (int i4 = (lo >> 2) + tid; i4 < (vecEnd >> 2); i4 += NT) {
    float4 x = l4[i4];
    rc += (x.x >= xcrit) + (x.y >= xcrit) + (x.z >= xcrit) + (x.w >= xcrit);
  }
  for (int i = vecEnd + tid; i < hi; i += NT) rc += (lrow[i] >= xcrit);
  for (int off = 32; off; off >>= 1) rc += __shfl_down(rc, off);
  if ((tid & 63) == 0) wiv[tid >> 6] = rc;
  __syncthreads();
  if (tid == 0) {
    int tot = 0;
    for (int w = 0; w < NW; w++) tot += wiv[w];
    atomicAdd(&out[Bn + 2 * (size_t)Bn * (K + 1) + b], (float)tot);
  }
}

extern "C" void kernel_launch(void* const* d_in, const int* in_sizes, int n_in,
                              void* d_out, int out_size, void* d_ws, size_t ws_size,
                              hipStream_t stream) {
  const float* logits = (const float*)d_in[0];
  const float* temp   = (const float*)d_in[1];
  const float* topp   = (const float*)d_in[2];
  const float* noise  = (const float*)d_in[3];
  const int*   topk   = (const int*)d_in[4];
  const int Bn = in_sizes[1];                         // 128
  const int V  = in_sizes[0] / Bn;                    // 128256
  const int K  = (out_size - 2 * Bn) / (2 * Bn) - 1;  // 20
  const int CS = (((V + S - 1) / S) + 3) & ~3;        // 8016

  char* w = (char*)d_ws;
  int*   histS  = (int*)w;    w += (size_t)Bn * S * NB * 4;
  float* massS  = (float*)w;  w += (size_t)Bn * S * NB * 4;
  float* scandV = (float*)w;  w += (size_t)Bn * S * SCAP * 4;
  int*   scandI = (int*)w;    w += (size_t)Bn * S * SCAP * 4;
  float* sMax   = (float*)w;  w += (size_t)Bn * S * 4;
  int*   sArg   = (int*)w;    w += (size_t)Bn * S * 4;
  float* sSum   = (float*)w;  w += (size_t)Bn * S * 4;
  int*   scnt   = (int*)w;    w += (size_t)Bn * S * 4;
  float* gbK    = (float*)w;  w += (size_t)Bn * S * 4;
  int*   gbI    = (int*)w;    w += (size_t)Bn * S * 4;
  float* l2V    = (float*)w;  w += (size_t)Bn * CAP2 * 4;
  int*   l2I    = (int*)w;    w += (size_t)Bn * CAP2 * 4;
  float* rowF   = (float*)w;  w += (size_t)Bn * 16 * 4;
  int*   rowI   = (int*)w;    w += (size_t)Bn * 16 * 4;
  int*   cnt2   = (int*)w;    w += (size_t)Bn * 4;

  dim3 gs(S, Bn);
  k1<<<gs, NT, 0, stream>>>(logits, V, CS, histS, sMax, sArg, sSum,
                            scandV, scandI, scnt);
  k2<<<Bn, NT, 0, stream>>>(temp, topp, topk, histS, sMax, sArg, sSum,
                            rowF, rowI, cnt2);
  k3<<<gs, NT, 0, stream>>>(logits, V, CS, rowF, rowI, massS);
  k4<<<Bn, NT, 0, stream>>>(logits, noise, V, K, scandV, scandI, scnt, massS,
                            rowF, rowI, (float*)d_out, Bn);
  k5<<<gs, NT, 0, stream>>>(logits, noise, V, CS, rowF, rowI, l2V, l2I, cnt2,
                            gbK, gbI);
  k6<<<Bn, NT, 0, stream>>>(logits, noise, V, K, l2V, l2I, cnt2, gbK, gbI,
                            rowF, rowI, (float*)d_out, Bn);
  k7<<<gs, NT, 0, stream>>>(logits, V, CS, rowF, rowI, (float*)d_out, Bn, K);
}

// Round 9
// 123.640 us; speedup vs baseline: 1.6246x; 1.1003x over previous
//
#include <hip/hip_runtime.h>
#include <float.h>
#include <math.h>

#define NT 256
#define NW (NT / 64)
#define S 16
#define NB 512
#define CAP1 1024
#define CAP2 2048
#define SCAP 512
#define LT 140
#define TGT 128
#define XMIN (-8.0f)
#define BINW (1.0f / 32.0f)
#define INVW (32.0f)
#define NSUB 1024
#define SUBCH (NSUB / NT)
#define SUBINV ((float)NSUB / BINW)
#define BCAP 512
#define SEPS 1e-5f

__device__ __forceinline__ int binOf(float x) {
  int bn = (int)floorf((x - XMIN) * INVW);
  return bn < 0 ? 0 : (bn > NB - 1 ? NB - 1 : bn);
}
__device__ __forceinline__ unsigned f2k(float f) {
  unsigned u = __float_as_uint(f);
  return (u & 0x80000000u) ? ~u : (u | 0x80000000u);
}
__device__ __forceinline__ float k2f(unsigned k) {
  return __uint_as_float((k & 0x80000000u) ? (k ^ 0x80000000u) : ~k);
}

// K1: slice resident in REGISTERS (8x float4/thread). One memory pass.
// hist+max -> local edge; sumexp(__expf) + collect + argmax; slice hist out;
// mode2 slice-scaled mass hist.
__global__ __launch_bounds__(NT, 4) void k1(const float* __restrict__ logits,
    const float* __restrict__ temp, const int* __restrict__ topkA,
    int V, int CS, int* __restrict__ histS,
    float* __restrict__ sMax, int* __restrict__ sArg, float* __restrict__ sSum,
    float* __restrict__ scandV, int* __restrict__ scandI, int* __restrict__ scnt,
    float* __restrict__ massS)
{
  const int s = blockIdx.x, b = blockIdx.y, tid = threadIdx.x;
  const int wid = tid >> 6;
  const float* lrow = logits + (size_t)b * V;
  const int lo = s * CS, hi = min(V, lo + CS);
  const int b4lo = lo >> 2, b4hi = hi >> 2;
  __shared__ int lh[4 * NB];
  __shared__ float wv[NW];
  __shared__ float shMax, shEdge;
  __shared__ int qn, shArg;
  __shared__ float qv[SCAP]; __shared__ int qi[SCAP];
  __shared__ float lm[NB];
  const float t = temp[b]; const int kk = topkA[b];
  const int mode = (t < SEPS) ? 0 : ((kk >= 1) ? 1 : 2);
  for (int j = tid; j < 4 * NB; j += NT) lh[j] = 0;
  if (mode == 2) for (int j = tid; j < NB; j += NT) lm[j] = 0.0f;
  if (tid == 0) { qn = 0; shArg = 0x7fffffff; }
  __syncthreads();

  const float4* l4 = reinterpret_cast<const float4*>(lrow);
  float4 r[8]; int idx0[8]; bool vl[8];
  #pragma unroll
  for (int u = 0; u < 8; u++) {
    int i4 = b4lo + tid + u * NT;
    vl[u] = (i4 < b4hi);
    idx0[u] = i4 << 2;
    r[u] = vl[u] ? l4[i4] : make_float4(-1e30f, -1e30f, -1e30f, -1e30f);
  }
  // pass A (regs): max + wave-priv count hist
  float bm = -1e30f;
  int* lhw = &lh[wid * NB];
  #pragma unroll
  for (int u = 0; u < 8; u++) {
    if (vl[u]) {
      float4 x = r[u];
      bm = fmaxf(bm, fmaxf(fmaxf(x.x, x.y), fmaxf(x.z, x.w)));
      atomicAdd(&lhw[binOf(x.x)], 1);
      atomicAdd(&lhw[binOf(x.y)], 1);
      atomicAdd(&lhw[binOf(x.z)], 1);
      atomicAdd(&lhw[binOf(x.w)], 1);
    }
  }
  for (int off = 32; off; off >>= 1) bm = fmaxf(bm, __shfl_down(bm, off));
  if ((tid & 63) == 0) wv[wid] = bm;
  __syncthreads();
  for (int j = tid; j < NB; j += NT)
    lh[j] += lh[NB + j] + lh[2 * NB + j] + lh[3 * NB + j];
  if (tid == 0) {
    float m = wv[0];
    for (int w = 1; w < NW; w++) m = fmaxf(m, wv[w]);
    shMax = m;
  }
  __syncthreads();
  // store slice hist (used by k2 for the true GLOBAL edge)
  int* hslice = histS + ((size_t)b * S + s) * NB;
  for (int j = tid; j < NB; j += NT) hslice[j] = lh[j];
  if (tid == 0) {
    int cum = 0, jsel = 0;
    for (int j = binOf(shMax); j >= 0; j--) {
      cum += lh[j];
      if (cum >= LT) { jsel = j; break; }
    }
    shEdge = XMIN + (jsel - 2) * BINW;   // 2-bin-margin local collect edge
  }
  __syncthreads();
  // pass B (regs): sumexp + collect + argmax-by-equality
  const float Ml = shMax, edge = shEdge;
  float sum = 0.0f;
  #pragma unroll
  for (int u = 0; u < 8; u++) {
    float4 x = r[u];
    sum += __expf(x.x - Ml) + __expf(x.y - Ml) + __expf(x.z - Ml) + __expf(x.w - Ml);
    float c; int id;
    c = x.x; id = idx0[u];
    if (c >= edge) { int p2 = atomicAdd(&qn, 1); if (p2 < SCAP) { qv[p2] = c; qi[p2] = id; } }
    if (c == Ml) atomicMin(&shArg, id);
    c = x.y; id = idx0[u] + 1;
    if (c >= edge) { int p2 = atomicAdd(&qn, 1); if (p2 < SCAP) { qv[p2] = c; qi[p2] = id; } }
    if (c == Ml) atomicMin(&shArg, id);
    c = x.z; id = idx0[u] + 2;
    if (c >= edge) { int p2 = atomicAdd(&qn, 1); if (p2 < SCAP) { qv[p2] = c; qi[p2] = id; } }
    if (c == Ml) atomicMin(&shArg, id);
    c = x.w; id = idx0[u] + 3;
    if (c >= edge) { int p2 = atomicAdd(&qn, 1); if (p2 < SCAP) { qv[p2] = c; qi[p2] = id; } }
    if (c == Ml) atomicMin(&shArg, id);
  }
  for (int off = 32; off; off >>= 1) sum += __shfl_down(sum, off);
  __syncthreads();
  if ((tid & 63) == 0) wv[wid] = sum;
  __syncthreads();
  if (tid == 0) {
    float ts = 0.0f;
    for (int w = 0; w < NW; w++) ts += wv[w];
    sSum[b * S + s] = ts;
    sMax[b * S + s] = shMax;
    sArg[b * S + s] = shArg;
    scnt[b * S + s] = min(qn, SCAP);
  }
  int qc = min(qn, SCAP);
  float* cvs = scandV + ((size_t)b * S + s) * SCAP;
  int*   cis = scandI + ((size_t)b * S + s) * SCAP;
  for (int j = tid; j < qc; j += NT) { cvs[j] = qv[j]; cis[j] = qi[j]; }
  // pass C (regs, mode2 only): slice-scaled mass hist
  if (mode == 2) {
    const float Msl = Ml / t;
    #pragma unroll
    for (int u = 0; u < 8; u++) {
      if (vl[u]) {
        float4 x = r[u];
        atomicAdd(&lm[binOf(x.x)], expf(x.x / t - Msl));
        atomicAdd(&lm[binOf(x.y)], expf(x.y / t - Msl));
        atomicAdd(&lm[binOf(x.z)], expf(x.z / t - Msl));
        atomicAdd(&lm[binOf(x.w)], expf(x.w / t - Msl));
      }
    }
    __syncthreads();
    float* msl = massS + ((size_t)b * S + s) * NB;
    for (int j = tid; j < NB; j += NT) msl[j] = lm[j];
  }
}

// K2: sum slice hists -> TRUE global edge; merge slices (M,gidx,logZ,mode);
// pool+filter+sort; top-K out; modes 0/1: sample+rank+finalize;
// mode 2: rescale-merge mass -> Bb.
__global__ __launch_bounds__(NT) void k2(const float* __restrict__ logits,
    const float* __restrict__ noise, const float* __restrict__ temp,
    const float* __restrict__ topp, const int* __restrict__ topkA,
    int V, int K, const int* __restrict__ histS,
    const float* __restrict__ sMax, const int* __restrict__ sArg,
    const float* __restrict__ sSum,
    const float* __restrict__ scandV, const int* __restrict__ scandI,
    const int* __restrict__ scnt, const float* __restrict__ massS,
    float* __restrict__ rowF, int* __restrict__ rowI, int* __restrict__ cnt2,
    float* __restrict__ out, int Bn)
{
  const int b = blockIdx.x, tid = threadIdx.x;
  __shared__ float cv[CAP1]; __shared__ int ci[CAP1];
  __shared__ float sv[CAP1]; __shared__ int si[CAP1];
  __shared__ float ev[CAP1];
  __shared__ int lc[NB];
  __shared__ float lmass[NB];
  __shared__ float fsum[NT];
  __shared__ float sMx[S], sSm[S], sfs[S];
  __shared__ int sAg[S], scl[S];
  __shared__ float wv[NW]; __shared__ int wi[NW];
  __shared__ int shI[2]; __shared__ float shF[8];
  __shared__ int nn;
  for (int j = tid; j < NB; j += NT) {
    int tot = 0;
    for (int s2 = 0; s2 < S; s2++) tot += histS[((size_t)b * S + s2) * NB + j];
    lc[j] = tot;
  }
  if (tid < S) {
    sMx[tid] = sMax[b * S + tid]; sSm[tid] = sSum[b * S + tid];
    sAg[tid] = sArg[b * S + tid]; scl[tid] = scnt[b * S + tid];
  }
  if (tid == 0) nn = 0;
  __syncthreads();
  const float t = temp[b], p = topp[b]; const int kk = topkA[b];
  const int mode = (t < SEPS) ? 0 : ((kk >= 1) ? 1 : 2);
  if (tid == 0) {
    float M = -FLT_MAX; int gi = 0x7fffffff;
    for (int s2 = 0; s2 < S; s2++) {
      float v = sMx[s2]; int ii = sAg[s2];
      if (v > M || (v == M && ii < gi)) { M = v; gi = ii; }
    }
    float Z = 0.0f;
    for (int s2 = 0; s2 < S; s2++) Z += sSm[s2] * expf(sMx[s2] - M);
    int cum = 0, bsel = 0;
    for (int j = NB - 1; j >= 0; j--) {
      cum += lc[j];
      if (cum >= TGT) { bsel = j; break; }
    }
    shF[0] = M; shF[1] = logf(Z);
    shF[2] = XMIN + (bsel - 2) * BINW;     // global filter edge, 2-bin margin
    shF[3] = (t >= SEPS) ? (M / t) : 0.0f;
    shI[0] = gi;
    rowF[b * 16 + 0] = M; rowF[b * 16 + 1] = shF[1]; rowF[b * 16 + 2] = shF[2];
    rowF[b * 16 + 3] = shF[3]; rowF[b * 16 + 4] = t; rowF[b * 16 + 5] = p;
    rowI[b * 16 + 0] = gi; rowI[b * 16 + 1] = mode; rowI[b * 16 + 2] = kk;
    cnt2[b] = 0;
  }
  __syncthreads();
  const float M = shF[0], logZ = shF[1], edgeC = shF[2], Ms = shF[3];
  const int gidx = shI[0];
  for (int s2 = 0; s2 < S; s2++) {
    const float* cvs = scandV + ((size_t)b * S + s2) * SCAP;
    const int*   cis = scandI + ((size_t)b * S + s2) * SCAP;
    int c = scl[s2];
    for (int j = tid; j < c; j += NT) {
      float x = cvs[j];
      if (x >= edgeC) {
        int p2 = atomicAdd(&nn, 1);
        if (p2 < CAP1) { cv[p2] = x; ci[p2] = cis[j]; }
      }
    }
  }
  __syncthreads();
  const int n = min(nn, CAP1);
  for (int c = tid; c < n; c += NT) {
    float v = cv[c]; int id = ci[c]; int r = 0;
    for (int j = 0; j < n; j++) {
      float w = cv[j];
      r += (w > v) || (w == v && ci[j] < id);
    }
    sv[r] = v; si[r] = id;
  }
  __syncthreads();
  float* out_idx = out + Bn;
  float* out_lp  = out + Bn + (size_t)Bn * (K + 1);
  for (int j = tid; j < K && j < n; j += NT) {
    out_idx[(size_t)b * (K + 1) + 1 + j] = (float)si[j];
    out_lp [(size_t)b * (K + 1) + 1 + j] = (sv[j] - M) - logZ;
  }

  if (mode == 2) {
    if (tid < S) sfs[tid] = expf((sMx[tid] - M) / t);
    __syncthreads();
    for (int j = tid; j < NB; j += NT) {
      float tot = 0.0f;
      for (int s2 = 0; s2 < S; s2++)
        tot += massS[((size_t)b * S + s2) * NB + j] * sfs[s2];
      lmass[j] = tot;
    }
    __syncthreads();
    const int CH = NB / NT;
    float cs = 0.0f;
    for (int j = tid * CH; j < (tid + 1) * CH; j++) cs += lmass[j];
    fsum[tid] = cs;
    __syncthreads();
    if (tid == 0) {
      float Z2 = 0.0f;
      for (int c = 0; c < NT; c++) Z2 += fsum[c];
      float W = p * Z2;
      float ca = 0.0f; int c = NT - 1;
      for (; c >= 0; c--) {
        if (ca + fsum[c] >= W) break;
        ca += fsum[c];
      }
      if (c < 0) c = 0;
      int Bb = c * CH, found = -1;
      for (int j = c * CH + CH - 1; j >= c * CH; j--) {
        if (ca + lmass[j] >= W) { found = j; break; }
        ca += lmass[j];
      }
      if (found >= 0) Bb = found;
      rowF[b * 16 + 6] = W; rowF[b * 16 + 7] = ca; rowI[b * 16 + 3] = Bb;
    }
    return;
  }

  int smp; float lx;
  if (mode == 0) {
    smp = gidx; lx = M;
  } else {
    const int keff = min(kk, n);
    for (int j = tid; j < keff; j += NT) ev[j] = expf(sv[j] / t - Ms);
    __syncthreads();
    if (tid == 0) {
      float Z = 0.0f;
      for (int j = 0; j < keff; j++) Z += ev[j];
      float W = p * Z;
      float cum = 0.0f; int m = 0;
      for (int j = 0; j < keff; j++) {
        if (cum < W) m++; else break;
        cum += ev[j];
      }
      shI[1] = m;
    }
    __syncthreads();
    const int m = shI[1];
    float key = -FLT_MAX; int kid = 0x7fffffff;
    for (int j = tid; j < m; j += NT) {
      float u = noise[(size_t)b * V + si[j]];
      float g = -logf(-logf(u));
      float kq = sv[j] / t + g;
      if (kq > key || (kq == key && si[j] < kid)) { key = kq; kid = si[j]; }
    }
    for (int off = 32; off; off >>= 1) {
      float ov = __shfl_down(key, off);
      int   oi = __shfl_down(kid, off);
      if (ov > key || (ov == key && oi < kid)) { key = ov; kid = oi; }
    }
    if ((tid & 63) == 0) { wv[tid >> 6] = key; wi[tid >> 6] = kid; }
    __syncthreads();
    if (tid == 0) {
      for (int w2 = 1; w2 < NW; w2++)
        if (wv[w2] > key || (wv[w2] == key && wi[w2] < kid)) { key = wv[w2]; kid = wi[w2]; }
      shI[1] = (kid == 0x7fffffff) ? 0 : kid;
    }
    __syncthreads();
    smp = shI[1];
    if (tid == 0) shF[4] = logits[(size_t)b * V + smp];
    __syncthreads();
    lx = shF[4];
  }
  const float tlp = (lx - M) - logZ;
  int rc = 0;
  for (int j = tid; j < n; j += NT) rc += (((sv[j] - M) - logZ) >= tlp) ? 1 : 0;
  for (int off = 32; off; off >>= 1) rc += __shfl_down(rc, off);
  __syncthreads();
  if ((tid & 63) == 0) wi[tid >> 6] = rc;
  __syncthreads();
  if (tid == 0) {
    int rank = 0;
    for (int w2 = 0; w2 < NW; w2++) rank += wi[w2];
    out[b] = (float)smp;
    out_idx[(size_t)b * (K + 1)] = (float)smp;
    out_lp [(size_t)b * (K + 1)] = tlp;
    out[Bn + 2 * (size_t)Bn * (K + 1) + b] = (float)rank;
  }
}

// K3 (mode2): collect boundary-bin elements + above-bin gumbel partials
__global__ __launch_bounds__(NT) void k3(const float* __restrict__ logits,
    const float* __restrict__ noise, int V, int CS,
    const float* __restrict__ rowF, const int* __restrict__ rowI,
    float* __restrict__ l2V, int* __restrict__ l2I, int* __restrict__ cnt2,
    float* __restrict__ gbK, int* __restrict__ gbI)
{
  const int s = blockIdx.x, b = blockIdx.y, tid = threadIdx.x;
  if (rowI[b * 16 + 1] != 2) return;
  const int Bb = rowI[b * 16 + 3];
  const float t = rowF[b * 16 + 4];
  const float* lrow = logits + (size_t)b * V;
  const float* nrow = noise + (size_t)b * V;
  const int lo = s * CS, hi = min(V, lo + CS);
  __shared__ int qn; __shared__ int sbase;
  __shared__ float qv[SCAP]; __shared__ int qi[SCAP];
  __shared__ float wv[NW]; __shared__ int wi[NW];
  if (tid == 0) qn = 0;
  __syncthreads();
  float key = -FLT_MAX; int kid = 0x7fffffff;
  for (int i = lo + tid; i < hi; i += NT) {
    float x = lrow[i];
    int bn = binOf(x);
    if (bn > Bb) {
      float g = -logf(-logf(nrow[i]));
      float kq = x / t + g;
      if (kq > key || (kq == key && i < kid)) { key = kq; kid = i; }
    } else if (bn == Bb) {
      int ppos = atomicAdd(&qn, 1);
      if (ppos < SCAP) { qv[ppos] = x; qi[ppos] = i; }
    }
  }
  for (int off = 32; off; off >>= 1) {
    float ov = __shfl_down(key, off);
    int   oi = __shfl_down(kid, off);
    if (ov > key || (ov == key && oi < kid)) { key = ov; kid = oi; }
  }
  if ((tid & 63) == 0) { wv[tid >> 6] = key; wi[tid >> 6] = kid; }
  __syncthreads();
  if (tid == 0) {
    for (int w = 1; w < NW; w++)
      if (wv[w] > key || (wv[w] == key && wi[w] < kid)) { key = wv[w]; kid = wi[w]; }
    gbK[b * S + s] = key; gbI[b * S + s] = kid;
  }
  int qc = min(qn, SCAP);
  if (tid == 0) sbase = atomicAdd(&cnt2[b], qc);
  __syncthreads();
  for (int j = tid; j < qc; j += NT) {
    int dst = sbase + j;
    if (dst < CAP2) { l2V[b * CAP2 + dst] = qv[j]; l2I[b * CAP2 + dst] = qi[j]; }
  }
}

// K4 (mode2): sub-bin histogram refinement, exact boundary, sample, xcrit
__global__ __launch_bounds__(NT) void k4(const float* __restrict__ logits,
    const float* __restrict__ noise, int V, int K,
    const float* __restrict__ l2V, const int* __restrict__ l2I,
    const int* __restrict__ cnt2,
    const float* __restrict__ gbK, const int* __restrict__ gbI,
    float* __restrict__ rowF, const int* __restrict__ rowI,
    float* __restrict__ out, int Bn)
{
  const int b = blockIdx.x, tid = threadIdx.x;
  if (rowI[b * 16 + 1] != 2) return;
  __shared__ float vals[CAP2]; __shared__ int idxs[CAP2]; __shared__ float evs[CAP2];
  __shared__ float subM[NSUB];
  __shared__ float fsum[NT];
  __shared__ int borderU[BCAP]; __shared__ int border[BCAP];
  __shared__ float wv[NW]; __shared__ int wi[NW];
  __shared__ int shBs, shLast, shBcnt;
  __shared__ float shCa;
  const int n2 = min(cnt2[b], CAP2);
  const float M = rowF[b * 16 + 0], logZ = rowF[b * 16 + 1], Ms = rowF[b * 16 + 3];
  const float t = rowF[b * 16 + 4];
  const float W = rowF[b * 16 + 6], CAv = rowF[b * 16 + 7];
  const int Bb = rowI[b * 16 + 3];
  const float binLo = XMIN + Bb * BINW;
  for (int j = tid; j < NSUB; j += NT) subM[j] = 0.0f;
  if (tid == 0) shBcnt = 0;
  __syncthreads();
  for (int j = tid; j < n2; j += NT) {
    float v = l2V[b * CAP2 + j]; int id = l2I[b * CAP2 + j];
    vals[j] = v; idxs[j] = id;
    float e = expf(v / t - Ms); evs[j] = e;
    int sb = (int)floorf((v - binLo) * SUBINV);
    sb = sb < 0 ? 0 : (sb > NSUB - 1 ? NSUB - 1 : sb);
    atomicAdd(&subM[sb], e);
  }
  __syncthreads();
  float cs = 0.0f;
  for (int j = tid * SUBCH; j < (tid + 1) * SUBCH; j++) cs += subM[j];
  fsum[tid] = cs;
  __syncthreads();
  if (tid == 0) {
    float cum = CAv; int Bs = -1; int c;
    for (c = NT - 1; c >= 0; c--) {
      if (cum + fsum[c] >= W) break;
      cum += fsum[c];
    }
    if (c >= 0) {
      for (int j = c * SUBCH + SUBCH - 1; j >= 0; j--) {
        if (cum + subM[j] >= W) { Bs = j; break; }
        cum += subM[j];
      }
    }
    shBs = Bs; shCa = cum;
  }
  __syncthreads();
  const int Bs = shBs;
  if (Bs >= 0) {
    for (int j = tid; j < n2; j += NT) {
      int sb = (int)floorf((vals[j] - binLo) * SUBINV);
      sb = sb < 0 ? 0 : (sb > NSUB - 1 ? NSUB - 1 : sb);
      if (sb == Bs) {
        int p2 = atomicAdd(&shBcnt, 1);
        if (p2 < BCAP) borderU[p2] = j;
      }
    }
  }
  __syncthreads();
  const int m = min(shBcnt, BCAP);
  for (int q = tid; q < m; q += NT) {
    int j = borderU[q];
    float v = vals[j]; int id = idxs[j]; int r = 0;
    for (int q2 = 0; q2 < m; q2++) {
      int j2 = borderU[q2];
      float w2 = vals[j2]; int id2 = idxs[j2];
      r += (w2 > v) || (w2 == v && id2 < id);
    }
    border[r] = j;
  }
  __syncthreads();
  if (tid == 0) {
    float cum = shCa; int lastq = -1;
    for (int q = 0; q < m; q++) {
      if (cum < W) lastq = q; else break;
      cum += evs[border[q]];
    }
    shLast = lastq;
  }
  __syncthreads();
  const int lastq = shLast;
  float key = -FLT_MAX; int kid = 0x7fffffff;
  for (int j = tid; j < n2; j += NT) {
    int sb = (int)floorf((vals[j] - binLo) * SUBINV);
    sb = sb < 0 ? 0 : (sb > NSUB - 1 ? NSUB - 1 : sb);
    if (sb > Bs) {
      float u = noise[(size_t)b * V + idxs[j]];
      float g = -logf(-logf(u));
      float kq = vals[j] / t + g;
      if (kq > key || (kq == key && idxs[j] < kid)) { key = kq; kid = idxs[j]; }
    }
  }
  for (int q = tid; q <= lastq; q += NT) {
    int j = border[q];
    float u = noise[(size_t)b * V + idxs[j]];
    float g = -logf(-logf(u));
    float kq = vals[j] / t + g;
    if (kq > key || (kq == key && idxs[j] < kid)) { key = kq; kid = idxs[j]; }
  }
  for (int off = 32; off; off >>= 1) {
    float ov = __shfl_down(key, off);
    int   oi = __shfl_down(kid, off);
    if (ov > key || (ov == key && oi < kid)) { key = ov; kid = oi; }
  }
  if ((tid & 63) == 0) { wv[tid >> 6] = key; wi[tid >> 6] = kid; }
  __syncthreads();
  if (tid == 0) {
    for (int w = 1; w < NW; w++)
      if (wv[w] > key || (wv[w] == key && wi[w] < kid)) { key = wv[w]; kid = wi[w]; }
    for (int s2 = 0; s2 < S; s2++) {
      float v = gbK[b * S + s2]; int ii = gbI[b * S + s2];
      if (v > key || (v == key && ii < kid)) { key = v; kid = ii; }
    }
    int smp = (kid == 0x7fffffff) ? 0 : kid;
    float lx = logits[(size_t)b * V + smp];
    float tlp = (lx - M) - logZ;
    unsigned loK = f2k(-3.0e38f);
    unsigned hiK = f2k(lx);
    while (hiK - loK > 1u) {
      unsigned mid = loK + ((hiK - loK) >> 1);
      float xm = k2f(mid);
      if (((xm - M) - logZ) >= tlp) hiK = mid; else loK = mid;
    }
    rowF[b * 16 + 9] = k2f(hiK);   // xcrit
    out[b] = (float)smp;
    out[Bn + (size_t)b * (K + 1)] = (float)smp;
    out[Bn + (size_t)Bn * (K + 1) + (size_t)b * (K + 1)] = tlp;
    out[Bn + 2 * (size_t)Bn * (K + 1) + b] = 0.0f;
  }
}

// K5 (mode2): rank = count(x >= xcrit) per slice -> atomic add
__global__ __launch_bounds__(NT) void k5(const float* __restrict__ logits,
    int V, int CS, const float* __restrict__ rowF, const int* __restrict__ rowI,
    float* __restrict__ out, int Bn, int K)
{
  const int s = blockIdx.x, b = blockIdx.y, tid = threadIdx.x;
  if (rowI[b * 16 + 1] != 2) return;
  const float xcrit = rowF[b * 16 + 9];
  const float* lrow = logits + (size_t)b * V;
  const int lo = s * CS, hi = min(V, lo + CS);
  __shared__ int wiv[NW];
  int rc = 0;
  const int vecEnd = lo + ((hi - lo) & ~3);
  const float4* l4 = reinterpret_cast<const float4*>(lrow);
  for (int i4 = (lo >> 2) + tid; i4 < (vecEnd >> 2); i4 += NT) {
    float4 x = l4[i4];
    rc += (x.x >= xcrit) + (x.y >= xcrit) + (x.z >= xcrit) + (x.w >= xcrit);
  }
  for (int i = vecEnd + tid; i < hi; i += NT) rc += (lrow[i] >= xcrit);
  for (int off = 32; off; off >>= 1) rc += __shfl_down(rc, off);
  if ((tid & 63) == 0) wiv[tid >> 6] = rc;
  __syncthreads();
  if (tid == 0) {
    int tot = 0;
    for (int w = 0; w < NW; w++) tot += wiv[w];
    atomicAdd(&out[Bn + 2 * (size_t)Bn * (K + 1) + b], (float)tot);
  }
}

extern "C" void kernel_launch(void* const* d_in, const int* in_sizes, int n_in,
                              void* d_out, int out_size, void* d_ws, size_t ws_size,
                              hipStream_t stream) {
  const float* logits = (const float*)d_in[0];
  const float* temp   = (const float*)d_in[1];
  const float* topp   = (const float*)d_in[2];
  const float* noise  = (const float*)d_in[3];
  const int*   topk   = (const int*)d_in[4];
  const int Bn = in_sizes[1];                         // 128
  const int V  = in_sizes[0] / Bn;                    // 128256
  const int K  = (out_size - 2 * Bn) / (2 * Bn) - 1;  // 20
  const int CS = (((V + S - 1) / S) + 3) & ~3;        // 8016

  char* w = (char*)d_ws;
  int*   histS  = (int*)w;    w += (size_t)Bn * S * NB * 4;
  float* massS  = (float*)w;  w += (size_t)Bn * S * NB * 4;
  float* scandV = (float*)w;  w += (size_t)Bn * S * SCAP * 4;
  int*   scandI = (int*)w;    w += (size_t)Bn * S * SCAP * 4;
  float* sMax   = (float*)w;  w += (size_t)Bn * S * 4;
  int*   sArg   = (int*)w;    w += (size_t)Bn * S * 4;
  float* sSum   = (float*)w;  w += (size_t)Bn * S * 4;
  int*   scnt   = (int*)w;    w += (size_t)Bn * S * 4;
  float* gbK    = (float*)w;  w += (size_t)Bn * S * 4;
  int*   gbI    = (int*)w;    w += (size_t)Bn * S * 4;
  float* l2V    = (float*)w;  w += (size_t)Bn * CAP2 * 4;
  int*   l2I    = (int*)w;    w += (size_t)Bn * CAP2 * 4;
  float* rowF   = (float*)w;  w += (size_t)Bn * 16 * 4;
  int*   rowI   = (int*)w;    w += (size_t)Bn * 16 * 4;
  int*   cnt2   = (int*)w;    w += (size_t)Bn * 4;

  dim3 gs(S, Bn);
  k1<<<gs, NT, 0, stream>>>(logits, temp, topk, V, CS, histS, sMax, sArg, sSum,
                            scandV, scandI, scnt, massS);
  k2<<<Bn, NT, 0, stream>>>(logits, noise, temp, topp, topk, V, K, histS,
                            sMax, sArg, sSum, scandV, scandI, scnt, massS,
                            rowF, rowI, cnt2, (float*)d_out, Bn);
  k3<<<gs, NT, 0, stream>>>(logits, noise, V, CS, rowF, rowI, l2V, l2I, cnt2,
                            gbK, gbI);
  k4<<<Bn, NT, 0, stream>>>(logits, noise, V, K, l2V, l2I, cnt2, gbK, gbI,
                            rowF, rowI, (float*)d_out, Bn);
  k5<<<gs, NT, 0, stream>>>(logits, V, CS, rowF, rowI, (float*)d_out, Bn, K);
}